// Round 4
// baseline (885.231 us; speedup 1.0000x reference)
//
#include <hip/hip_runtime.h>
#include <hip/hip_bf16.h>
#include <stdint.h>

// ---------------- static problem sizes ----------------
#define BB    32
#define NPER  1024
#define NTOT  32768
#define DD    128
#define HH    4
#define HD    32
#define LL    3
#define DFF   2048
#define INDIM 64
#define QKSCALE 0.17677669529663687f

typedef unsigned short u16;
typedef short bf16x8 __attribute__((ext_vector_type(8)));   // 8 bf16 (4 VGPRs)
typedef float f32x4 __attribute__((ext_vector_type(4)));

__device__ __forceinline__ float bf2f(u16 v){
  unsigned u = ((unsigned)v) << 16; float f; __builtin_memcpy(&f, &u, 4); return f;
}
__device__ __forceinline__ u16 f2bf(float f){
  unsigned u; __builtin_memcpy(&u, &f, 4);
  unsigned lsb = (u >> 16) & 1u;
  u += 0x7fffu + lsb;              // round-to-nearest-even
  return (u16)(u >> 16);
}

// ---------------- workspace layout (bytes) ----------------
constexpr size_t OFF_FLAG   = 0;
constexpr size_t OFF_STARTS = 256;
constexpr size_t OFF_BIN    = 1024;
constexpr size_t OFF_BQKV   = OFF_BIN   + 128*4;
constexpr size_t OFF_BO     = OFF_BQKV  + 1152*4;
constexpr size_t OFF_B1     = OFF_BO    + 384*4;
constexpr size_t OFF_B2     = OFF_B1    + 6144*4;
constexpr size_t OFF_LN1G   = OFF_B2    + 384*4;
constexpr size_t OFF_LN1B   = OFF_LN1G  + 384*4;
constexpr size_t OFF_LN2G   = OFF_LN1B  + 384*4;
constexpr size_t OFF_LN2B   = OFF_LN2G  + 384*4;
constexpr size_t OFF_XB     = 40960;
constexpr size_t OFF_WINB   = OFF_XB    + (size_t)2097152*2;
constexpr size_t OFF_WQKVB  = OFF_WINB  + (size_t)8192*2;
constexpr size_t OFF_WOB    = OFF_WQKVB + (size_t)147456*2;
constexpr size_t OFF_W1B    = OFF_WOB   + (size_t)49152*2;
constexpr size_t OFF_W2B    = OFF_W1B   + (size_t)786432*2;
constexpr size_t OFF_CUR    = OFF_W2B   + (size_t)786432*2;
constexpr size_t OFF_TMP    = OFF_CUR   + (size_t)4194304*4;
constexpr size_t OFF_CURB   = OFF_TMP   + (size_t)4194304*4;
constexpr size_t OFF_QKVB   = OFF_CURB  + (size_t)4194304*2;
constexpr size_t OFF_ATTNOB = OFF_QKVB  + (size_t)12582912*2;
constexpr size_t OFF_ACTB   = OFF_ATTNOB+ (size_t)4194304*2;     // (unused now)
constexpr size_t OFF_MASK   = OFF_ACTB  + (size_t)16777216*2;
constexpr size_t OFF_VT     = OFF_MASK  + (size_t)NTOT*4;
constexpr size_t OFF_RED    = OFF_VT    + (size_t)4096*1024*2;
constexpr size_t OFF_CNT    = OFF_RED   + (size_t)32*8*128*4;

// ---------------- dtype detection ----------------
__device__ __forceinline__ int plaus(unsigned bits){
  if ((bits << 1) == 0u) return 1;
  unsigned e = (bits >> 23) & 0xFFu;
  return (e >= 100u && e <= 140u) ? 1 : 0;
}
__global__ void detect_kernel(const unsigned* __restrict__ x, int* __restrict__ flag){
  __shared__ int red[256];
  int t = threadIdx.x, c = 0;
  for (int i = t; i < 2048; i += 256){
    unsigned w = x[i];
    c += (plaus(w << 16) & plaus(w & 0xFFFF0000u));
  }
  red[t] = c; __syncthreads();
  for (int s = 128; s > 0; s >>= 1){ if (t < s) red[t] += red[t+s]; __syncthreads(); }
  if (t == 0) *flag = (red[0] >= 1229) ? 1 : 0;
}

__global__ void conv2bf16_kernel(const void* __restrict__ src, u16* __restrict__ dst,
                                 int n, const int* __restrict__ flag){
  int isb = *flag;
  for (int i = blockIdx.x*blockDim.x + threadIdx.x; i < n; i += gridDim.x*blockDim.x){
    if (isb) dst[i] = ((const u16*)src)[i];
    else     dst[i] = f2bf(((const float*)src)[i]);
  }
}
__global__ void conv2f32_kernel(const void* __restrict__ src, float* __restrict__ dst,
                                int n, const int* __restrict__ flag){
  int isb = *flag;
  for (int i = blockIdx.x*blockDim.x + threadIdx.x; i < n; i += gridDim.x*blockDim.x){
    dst[i] = isb ? bf2f(((const u16*)src)[i]) : ((const float*)src)[i];
  }
}

__global__ void starts_kernel(const int* __restrict__ batch, int* __restrict__ starts){
  int b = threadIdx.x;
  if (b < BB){
    int lo = 0, hi = NTOT;
    while (lo < hi){ int mid = (lo + hi) >> 1; if (batch[mid] < b) lo = mid + 1; else hi = mid; }
    starts[b] = lo;
  }
}

// ---------------- legacy small GEMM (input projection only) ----------------
__global__ __launch_bounds__(256) void gemm_bf16(
    const u16* __restrict__ A, int lda,
    const u16* __restrict__ W, int ldw,
    const float* __restrict__ bias,
    float* __restrict__ Cf, u16* __restrict__ Cb,
    int N, int K, int flags)
{
  __shared__ __align__(16) u16 At[64][32];
  __shared__ __align__(16) u16 Wt[64][32];
  const int t = threadIdx.x;
  const int m0 = blockIdx.x * 64, n0 = blockIdx.y * 64;
  const int wave = t >> 6, lane = t & 63;
  const int quad = lane >> 4, l16 = lane & 15;
  const int lr = t >> 2, lc = (t & 3) * 8;

  f32x4 acc[4];
  #pragma unroll
  for (int i = 0; i < 4; ++i){ acc[i][0]=0.f; acc[i][1]=0.f; acc[i][2]=0.f; acc[i][3]=0.f; }

  const u16* Arow = A + (size_t)(m0 + lr) * lda + lc;
  const u16* Wrow = W + (size_t)(n0 + lr) * ldw + lc;

  for (int k0 = 0; k0 < K; k0 += 32){
    uint4 av = *(const uint4*)(Arow + k0);
    uint4 wv = *(const uint4*)(Wrow + k0);
    __syncthreads();
    *(uint4*)&At[lr][lc] = av;
    *(uint4*)&Wt[lr][lc] = wv;
    __syncthreads();
    bf16x8 af = *(const bf16x8*)&At[wave*16 + l16][quad*8];
    #pragma unroll
    for (int nt = 0; nt < 4; ++nt){
      bf16x8 wf = *(const bf16x8*)&Wt[nt*16 + l16][quad*8];
      acc[nt] = __builtin_amdgcn_mfma_f32_16x16x32_bf16(af, wf, acc[nt], 0, 0, 0);
    }
  }
  const int row = m0 + wave*16 + quad*4;
  #pragma unroll
  for (int nt = 0; nt < 4; ++nt){
    const int col = n0 + nt*16 + l16;
    const float bv = bias ? bias[col] : 0.f;
    #pragma unroll
    for (int r = 0; r < 4; ++r){
      size_t idx = (size_t)(row + r) * N + col;
      float v = acc[nt][r] + bv;
      if (flags & 1) v = fmaxf(v, 0.f);
      if (Cf) Cf[idx] = v;
      if (Cb) Cb[idx] = f2bf(v);
    }
  }
}

// ---------------- scatter projected nodes into padded layout + mask ----------------
__global__ __launch_bounds__(128) void scatter_kernel(
    const float* __restrict__ hlin, const int* __restrict__ batch,
    const int* __restrict__ starts, float* __restrict__ cur,
    u16* __restrict__ curb, float* __restrict__ mask)
{
  int i = blockIdx.x, t = threadIdx.x;
  int g = batch[i];
  int p = i - starts[g];
  float v = hlin[(size_t)i*DD + t];
  float s = v;
  #pragma unroll
  for (int off = 32; off; off >>= 1) s += __shfl_xor(s, off);
  __shared__ float sh[2];
  if ((t & 63) == 0) sh[t >> 6] = s;
  __syncthreads();
  float rowsum = sh[0] + sh[1];
  if ((unsigned)p < (unsigned)NPER && (unsigned)g < (unsigned)BB){
    size_t j = (size_t)g*NPER + p;
    cur[j*DD + t]  = v;
    curb[j*DD + t] = f2bf(v);
    if (t == 0) mask[j] = (rowsum != 0.f) ? 1.f : 0.f;
  }
}

// ---------------- V transpose ----------------
__global__ __launch_bounds__(256) void vtrans_kernel(const u16* __restrict__ qkvb,
                                                     u16* __restrict__ vt)
{
  __shared__ u16 tile[64][33];
  const int t = threadIdx.x;
  const int s0 = blockIdx.x * 64, h = blockIdx.y, b = blockIdx.z;
  {
    int s = t >> 2, dc = (t & 3) * 8;
    uint4 v = *(const uint4*)(qkvb + (size_t)(b*NPER + s0 + s)*384 + 256 + h*HD + dc);
    u16 tmp[8]; __builtin_memcpy(tmp, &v, 16);
    #pragma unroll
    for (int j = 0; j < 8; ++j) tile[s][dc + j] = tmp[j];
  }
  __syncthreads();
  {
    int d = t >> 3, sc = (t & 7) * 8;
    u16 o[8];
    #pragma unroll
    for (int j = 0; j < 8; ++j) o[j] = tile[sc + j][d];
    uint4 ov; __builtin_memcpy(&ov, o, 16);
    *(uint4*)(vt + (size_t)((b*HH + h)*HD + d)*NPER + s0 + sc) = ov;
  }
}

// ---------------- MFMA flash attention ----------------
__global__ __launch_bounds__(256) void fattn_kernel(
    const u16* __restrict__ qkvb, const u16* __restrict__ vt,
    u16* __restrict__ attnob)
{
  __shared__ __align__(16) u16 Klds[64*40];
  __shared__ __align__(16) u16 Vtl[32*72];
  __shared__ __align__(16) u16 Plds[4][16*72];

  const int t = threadIdx.x;
  const int wave = t >> 6, lane = t & 63;
  const int quad = lane >> 4, l16 = lane & 15;
  const int q0 = blockIdx.x * 64;
  const int h = blockIdx.y, b = blockIdx.z;
  const size_t qkvbase = (size_t)b * NPER * 384;

  bf16x8 qf;
  {
    const u16* qp = qkvb + qkvbase + (size_t)(q0 + wave*16 + l16)*384 + h*HD + quad*8;
    uint4 qv = *(const uint4*)qp;
    u16 raw[8]; __builtin_memcpy(raw, &qv, 16);
    #pragma unroll
    for (int j = 0; j < 8; ++j) qf[j] = (short)f2bf(bf2f(raw[j]) * QKSCALE);
  }

  float lsum[4] = {0.f, 0.f, 0.f, 0.f};
  f32x4 o0 = {0.f,0.f,0.f,0.f}, o1 = {0.f,0.f,0.f,0.f};
  u16* pw = &Plds[wave][0];

  const int ks = t >> 2,  kdc = (t & 3) * 8;
  const int vd = t >> 3,  vsc = (t & 7) * 8;

  for (int kt = 0; kt < 16; ++kt){
    __syncthreads();
    {
      uint4 kv = *(const uint4*)(qkvb + qkvbase + (size_t)(kt*64 + ks)*384 + 128 + h*HD + kdc);
      *(uint4*)&Klds[ks*40 + kdc] = kv;
      uint4 vv = *(const uint4*)(vt + (size_t)((b*HH + h)*HD + vd)*NPER + kt*64 + vsc);
      *(uint4*)&Vtl[vd*72 + vsc] = vv;
    }
    __syncthreads();

    f32x4 sfr[4];
    #pragma unroll
    for (int nt = 0; nt < 4; ++nt){
      bf16x8 kf = *(const bf16x8*)&Klds[(nt*16 + l16)*40 + quad*8];
      f32x4 z = {0.f,0.f,0.f,0.f};
      sfr[nt] = __builtin_amdgcn_mfma_f32_16x16x32_bf16(qf, kf, z, 0, 0, 0);
    }

    float psum[4] = {0.f, 0.f, 0.f, 0.f};
    #pragma unroll
    for (int nt = 0; nt < 4; ++nt){
      #pragma unroll
      for (int r = 0; r < 4; ++r){
        float e = __expf(sfr[nt][r]);
        psum[r] += e;
        pw[(quad*4 + r)*72 + nt*16 + l16] = f2bf(e);
      }
    }
    #pragma unroll
    for (int r = 0; r < 4; ++r){
      float s = psum[r];
      s += __shfl_xor(s, 1); s += __shfl_xor(s, 2);
      s += __shfl_xor(s, 4); s += __shfl_xor(s, 8);
      lsum[r] += s;
    }
    __syncthreads();

    #pragma unroll
    for (int c = 0; c < 2; ++c){
      bf16x8 pf = *(const bf16x8*)&pw[l16*72 + c*32 + quad*8];
      bf16x8 v0 = *(const bf16x8*)&Vtl[(l16     )*72 + c*32 + quad*8];
      bf16x8 v1 = *(const bf16x8*)&Vtl[(16 + l16)*72 + c*32 + quad*8];
      o0 = __builtin_amdgcn_mfma_f32_16x16x32_bf16(pf, v0, o0, 0, 0, 0);
      o1 = __builtin_amdgcn_mfma_f32_16x16x32_bf16(pf, v1, o1, 0, 0, 0);
    }
  }

  #pragma unroll
  for (int r = 0; r < 4; ++r){
    float inv = 1.f / lsum[r];
    int row = q0 + wave*16 + quad*4 + r;
    size_t base = (size_t)(b*NPER + row)*DD + h*HD;
    attnob[base + l16]      = f2bf(o0[r] * inv);
    attnob[base + 16 + l16] = f2bf(o1[r] * inv);
  }
}

// ---------------- LN epilogue (wave owns 16 rows): out = LN(resid + O + bias) ----------------
__device__ __forceinline__ void epilogue_ln64(
    const f32x4 O[8], int m0, int wave, int quad, int l16,
    const float* __restrict__ bias, const float* __restrict__ g,
    const float* __restrict__ beta, float* __restrict__ cur,
    u16* __restrict__ curb)
{
  #pragma unroll
  for (int rr = 0; rr < 4; ++rr){
    int row = m0 + wave*16 + quad*4 + rr;
    float vs[8], sum = 0.f;
    #pragma unroll
    for (int nt = 0; nt < 8; ++nt){
      int col = nt*16 + l16;
      float v = O[nt][rr] + bias[col] + cur[(size_t)row*DD + col];
      vs[nt] = v; sum += v;
    }
    sum += __shfl_xor(sum, 1); sum += __shfl_xor(sum, 2);
    sum += __shfl_xor(sum, 4); sum += __shfl_xor(sum, 8);
    float mean = sum * (1.f/DD);
    float sq = 0.f;
    #pragma unroll
    for (int nt = 0; nt < 8; ++nt){ float d = vs[nt] - mean; sq += d*d; }
    sq += __shfl_xor(sq, 1); sq += __shfl_xor(sq, 2);
    sq += __shfl_xor(sq, 4); sq += __shfl_xor(sq, 8);
    float rs = rsqrtf(sq * (1.f/DD) + 1e-5f);
    #pragma unroll
    for (int nt = 0; nt < 8; ++nt){
      int col = nt*16 + l16;
      float o = (vs[nt] - mean)*rs*g[col] + beta[col];
      cur[(size_t)row*DD + col]  = o;
      curb[(size_t)row*DD + col] = f2bf(o);
    }
  }
}

// ---------------- 64-row-block GEMM, W (128x128 slice) in LDS, A-frags in regs ----------------
// mode 0: outb[row][nb*128+col] = bf16(O + bias)   (QKV; grid.y = N/128 slices)
// mode 1: LN epilogue (Wo + LN1)
__global__ __launch_bounds__(256) void wgemm_kernel(
    const u16* __restrict__ A,        // [M][128] bf16
    const u16* __restrict__ Wbase,    // [gridDim.y*128][128] bf16
    const float* __restrict__ biasb,  // [gridDim.y*128]
    int mode,
    u16* __restrict__ outb, int opitch,
    float* __restrict__ cur, u16* __restrict__ curb,
    const float* __restrict__ g, const float* __restrict__ beta)
{
  __shared__ __align__(16) u16 Wl[16384];          // 128x128, XOR-swizzled chunks
  const int t = threadIdx.x, wave = t >> 6, lane = t & 63;
  const int quad = lane >> 4, l16 = lane & 15;
  const int m0 = blockIdx.x * 64, nb = blockIdx.y;
  const u16* Wsl = Wbase + (size_t)nb * 16384;
  const float* bias = biasb + nb * 128;

  // stage W slice: slot s (16B) -> row r = s>>4, stored chunk = s&15, src chunk = (s&15)^(r&15)
  #pragma unroll
  for (int j = 0; j < 8; ++j){
    int s = t + 256*j;
    int r = s >> 4, cx = (s & 15) ^ (r & 15);
    *(uint4*)&Wl[s*8] = *(const uint4*)(Wsl + (size_t)r*128 + cx*8);
  }
  // A-frags in regs: rows m0 + wave*16 + l16
  bf16x8 af[4];
  #pragma unroll
  for (int kk = 0; kk < 4; ++kk)
    af[kk] = *(const bf16x8*)(A + (size_t)(m0 + wave*16 + l16)*128 + kk*32 + quad*8);
  __syncthreads();

  f32x4 O[8];
  #pragma unroll
  for (int nt = 0; nt < 8; ++nt){ O[nt][0]=0.f; O[nt][1]=0.f; O[nt][2]=0.f; O[nt][3]=0.f; }

  #pragma unroll
  for (int nt = 0; nt < 8; ++nt){
    int row = nt*16 + l16;
    bf16x8 wf[4];
    #pragma unroll
    for (int kk = 0; kk < 4; ++kk)
      wf[kk] = *(const bf16x8*)&Wl[(row*16 + ((kk*4 + quad) ^ l16))*8];
    #pragma unroll
    for (int kk = 0; kk < 4; ++kk)
      O[nt] = __builtin_amdgcn_mfma_f32_16x16x32_bf16(af[kk], wf[kk], O[nt], 0, 0, 0);
  }

  if (mode == 0){
    #pragma unroll
    for (int rr = 0; rr < 4; ++rr){
      int row = m0 + wave*16 + quad*4 + rr;
      #pragma unroll
      for (int nt = 0; nt < 8; ++nt){
        int col = nt*16 + l16;
        outb[(size_t)row*opitch + nb*128 + col] = f2bf(O[nt][rr] + bias[col]);
      }
    }
  } else {
    epilogue_ln64(O, m0, wave, quad, l16, bias, g, beta, cur, curb);
  }
}

// ---------------- fused FFN, 64-row blocks, double-buffered W LDS ----------------
// O = relu(A@W1^T+b1)@W2^T + b2; out = LN2(cur + O)
__global__ __launch_bounds__(256) void ffn_kernel(
    const u16* __restrict__ Ag,       // CURB [M][128]
    const u16* __restrict__ W1g,      // [2048][128]
    const u16* __restrict__ W2g,      // [128][2048]
    const float* __restrict__ b1,
    const float* __restrict__ b2,
    const float* __restrict__ g, const float* __restrict__ beta,
    float* __restrict__ cur, u16* __restrict__ curb)
{
  __shared__ __align__(16) u16 W1l[2][8192];       // 64x128 chunk, swizzled, x2 buf
  __shared__ __align__(16) u16 W2l[2][8192];       // 128x64 chunk, swizzled, x2 buf
  __shared__ __align__(16) u16 Pl[4][16*72];       // per-wave act, pitch 72

  const int t = threadIdx.x, wave = t >> 6, lane = t & 63;
  const int quad = lane >> 4, l16 = lane & 15;
  const int m0 = blockIdx.x * 64;
  u16* Pw = &Pl[wave][0];

  // A-frags in regs (wave owns 16 rows)
  bf16x8 af[4];
  #pragma unroll
  for (int kk = 0; kk < 4; ++kk)
    af[kk] = *(const bf16x8*)(Ag + (size_t)(m0 + wave*16 + l16)*128 + kk*32 + quad*8);

  f32x4 O[8];
  #pragma unroll
  for (int nt = 0; nt < 8; ++nt){ O[nt][0]=0.f; O[nt][1]=0.f; O[nt][2]=0.f; O[nt][3]=0.f; }

  uint4 w1r[4], w2r[4];
  auto ldW = [&](int dffc){
    #pragma unroll
    for (int j = 0; j < 4; ++j){
      int s = t + 256*j;
      { int r = s >> 4, cx = (s & 15) ^ (r & 15);
        w1r[j] = *(const uint4*)(W1g + (size_t)(dffc + r)*128 + cx*8); }
      { int r = s >> 3, cx = (s & 7) ^ (r & 7);
        w2r[j] = *(const uint4*)(W2g + (size_t)r*DFF + dffc + cx*8); }
    }
  };

  // prologue: chunk 0 -> buf 0
  ldW(0);
  #pragma unroll
  for (int j = 0; j < 4; ++j){
    *(uint4*)&W1l[0][(t + 256*j)*8] = w1r[j];
    *(uint4*)&W2l[0][(t + 256*j)*8] = w2r[j];
  }
  __syncthreads();

  for (int c = 0; c < 32; ++c){
    const int buf = c & 1;
    if (c + 1 < 32) ldW((c + 1)*64);               // loads in flight across compute

    // phase 1: act = relu(A @ W1c^T + b1) -> P (wave-private, bf16)
    #pragma unroll
    for (int nt = 0; nt < 4; ++nt){
      int row = nt*16 + l16;                       // dff-local row
      bf16x8 wf[4];
      #pragma unroll
      for (int kk = 0; kk < 4; ++kk)
        wf[kk] = *(const bf16x8*)&W1l[buf][(row*16 + ((kk*4 + quad) ^ l16))*8];
      float b1v = b1[c*64 + row];
      f32x4 s = {0.f,0.f,0.f,0.f};
      #pragma unroll
      for (int kk = 0; kk < 4; ++kk)
        s = __builtin_amdgcn_mfma_f32_16x16x32_bf16(af[kk], wf[kk], s, 0, 0, 0);
      #pragma unroll
      for (int rr = 0; rr < 4; ++rr)
        Pw[(quad*4 + rr)*72 + nt*16 + l16] = f2bf(fmaxf(s[rr] + b1v, 0.f));
    }
    // wave-internal LDS RAW: drain before cross-lane read
    asm volatile("s_waitcnt lgkmcnt(0)" ::: "memory");

    // phase 2: O += P @ W2c^T
    bf16x8 pf[2];
    #pragma unroll
    for (int kk = 0; kk < 2; ++kk)
      pf[kk] = *(const bf16x8*)&Pw[l16*72 + kk*32 + quad*8];
    #pragma unroll
    for (int nt = 0; nt < 8; ++nt){
      int row = nt*16 + l16;                       // output-col row of W2
      bf16x8 wf[2];
      #pragma unroll
      for (int kk = 0; kk < 2; ++kk)
        wf[kk] = *(const bf16x8*)&W2l[buf][(row*8 + ((kk*4 + quad) ^ (l16 & 7)))*8];
      #pragma unroll
      for (int kk = 0; kk < 2; ++kk)
        O[nt] = __builtin_amdgcn_mfma_f32_16x16x32_bf16(pf[kk], wf[kk], O[nt], 0, 0, 0);
    }

    // stage chunk c+1 into the other buffer; single barrier per chunk
    if (c + 1 < 32){
      #pragma unroll
      for (int j = 0; j < 4; ++j){
        *(uint4*)&W1l[buf ^ 1][(t + 256*j)*8] = w1r[j];
        *(uint4*)&W2l[buf ^ 1][(t + 256*j)*8] = w2r[j];
      }
      __syncthreads();
    }
  }

  epilogue_ln64(O, m0, wave, quad, l16, b2, g, beta, cur, curb);
}

// ---------------- final masked mean, two-stage ----------------
__global__ __launch_bounds__(128) void reduce1_kernel(
    const float* __restrict__ cur, const float* __restrict__ mask,
    float* __restrict__ partial, float* __restrict__ cnt)
{
  int b = blockIdx.x, c = blockIdx.y, t = threadIdx.x;
  float acc = 0.f, cn = 0.f;
  for (int s = c*128; s < c*128 + 128; ++s){
    float mk = mask[b*NPER + s];
    acc += cur[(size_t)(b*NPER + s)*DD + t] * mk;
    cn += mk;
  }
  partial[(size_t)(b*8 + c)*DD + t] = acc;
  if (t == 0) cnt[b*8 + c] = cn;
}
__global__ __launch_bounds__(128) void reduce2_kernel(
    const float* __restrict__ partial, const float* __restrict__ cnt,
    const int* __restrict__ flag, void* __restrict__ out)
{
  int b = blockIdx.x, t = threadIdx.x;
  float acc = 0.f, cn = 0.f;
  #pragma unroll
  for (int c = 0; c < 8; ++c){
    acc += partial[(size_t)(b*8 + c)*DD + t];
    cn  += cnt[b*8 + c];
  }
  float val = acc / cn;
  if (*flag) ((u16*)out)[b*DD + t] = f2bf(val);
  else       ((float*)out)[b*DD + t] = val;
}

// ---------------- host ----------------
extern "C" void kernel_launch(void* const* d_in, const int* in_sizes, int n_in,
                              void* d_out, int out_size, void* d_ws, size_t ws_size,
                              hipStream_t stream)
{
  (void)in_sizes; (void)n_in; (void)out_size; (void)ws_size;
  char* ws = (char*)d_ws;
  int*   flag   = (int*)(ws + OFF_FLAG);
  int*   starts = (int*)(ws + OFF_STARTS);
  float* BIN  = (float*)(ws + OFF_BIN);
  float* BQKV = (float*)(ws + OFF_BQKV);
  float* BO   = (float*)(ws + OFF_BO);
  float* B1   = (float*)(ws + OFF_B1);
  float* B2   = (float*)(ws + OFF_B2);
  float* LN1G = (float*)(ws + OFF_LN1G);
  float* LN1B = (float*)(ws + OFF_LN1B);
  float* LN2G = (float*)(ws + OFF_LN2G);
  float* LN2B = (float*)(ws + OFF_LN2B);
  u16* XB    = (u16*)(ws + OFF_XB);
  u16* WINB  = (u16*)(ws + OFF_WINB);
  u16* WQKVB = (u16*)(ws + OFF_WQKVB);
  u16* WOB   = (u16*)(ws + OFF_WOB);
  u16* W1B   = (u16*)(ws + OFF_W1B);
  u16* W2B   = (u16*)(ws + OFF_W2B);
  float* CUR = (float*)(ws + OFF_CUR);
  float* TMP = (float*)(ws + OFF_TMP);
  u16* CURB  = (u16*)(ws + OFF_CURB);
  u16* QKVB  = (u16*)(ws + OFF_QKVB);
  u16* ATTNOB= (u16*)(ws + OFF_ATTNOB);
  float* MASK= (float*)(ws + OFF_MASK);
  u16* VT    = (u16*)(ws + OFF_VT);
  float* RED = (float*)(ws + OFF_RED);
  float* CNT = (float*)(ws + OFF_CNT);

  detect_kernel<<<1, 256, 0, stream>>>((const unsigned*)d_in[0], flag);
  starts_kernel<<<1, 64, 0, stream>>>((const int*)d_in[1], starts);

  auto cb = [&](const void* s, u16* dp, int n){
    conv2bf16_kernel<<<(n + 1023)/1024, 256, 0, stream>>>(s, dp, n, flag);
  };
  auto cf = [&](const void* s, float* dp, int n){
    conv2f32_kernel<<<(n + 1023)/1024, 256, 0, stream>>>(s, dp, n, flag);
  };
  cb(d_in[0],  XB,    NTOT*INDIM);
  cb(d_in[2],  WINB,  DD*INDIM);
  cb(d_in[4],  WQKVB, LL*3*DD*DD);
  cb(d_in[6],  WOB,   LL*DD*DD);
  cb(d_in[8],  W1B,   LL*DFF*DD);
  cb(d_in[10], W2B,   LL*DD*DFF);
  cf(d_in[3],  BIN,   DD);
  cf(d_in[5],  BQKV,  LL*3*DD);
  cf(d_in[7],  BO,    LL*DD);
  cf(d_in[9],  B1,    LL*DFF);
  cf(d_in[11], B2,    LL*DD);
  cf(d_in[12], LN1G,  LL*DD);
  cf(d_in[13], LN1B,  LL*DD);
  cf(d_in[14], LN2G,  LL*DD);
  cf(d_in[15], LN2B,  LL*DD);

  gemm_bf16<<<dim3(NTOT/64, DD/64), 256, 0, stream>>>(
      XB, INDIM, WINB, INDIM, BIN, TMP, nullptr, DD, INDIM, 0);
  scatter_kernel<<<NTOT, 128, 0, stream>>>(TMP, (const int*)d_in[1], starts, CUR, CURB, MASK);

  for (int l = 0; l < LL; ++l){
    // QKV: 3 N-slices of 128
    wgemm_kernel<<<dim3(NTOT/64, 3), 256, 0, stream>>>(
        CURB, WQKVB + (size_t)l*3*DD*DD, BQKV + l*3*DD, 0,
        QKVB, 384, nullptr, nullptr, nullptr, nullptr);
    vtrans_kernel<<<dim3(NPER/64, HH, BB), 256, 0, stream>>>(QKVB, VT);
    fattn_kernel<<<dim3(NPER/64, HH, BB), 256, 0, stream>>>(QKVB, VT, ATTNOB);
    // Wo + residual + LN1
    wgemm_kernel<<<dim3(NTOT/64, 1), 256, 0, stream>>>(
        ATTNOB, WOB + (size_t)l*DD*DD, BO + l*DD, 1,
        nullptr, 0, CUR, CURB, LN1G + l*DD, LN1B + l*DD);
    // fused FFN + residual + LN2
    ffn_kernel<<<dim3(NTOT/64), 256, 0, stream>>>(
        CURB, W1B + (size_t)l*DFF*DD, W2B + (size_t)l*DD*DFF,
        B1 + l*DFF, B2 + l*DD, LN2G + l*DD, LN2B + l*DD, CUR, CURB);
  }

  reduce1_kernel<<<dim3(BB, 8), 128, 0, stream>>>(CUR, MASK, RED, CNT);
  reduce2_kernel<<<BB, 128, 0, stream>>>(RED, CNT, flag, d_out);
}

// Round 5
// 884.815 us; speedup vs baseline: 1.0005x; 1.0005x over previous
//
#include <hip/hip_runtime.h>
#include <hip/hip_bf16.h>
#include <stdint.h>

// ---------------- static problem sizes ----------------
#define BB    32
#define NPER  1024
#define NTOT  32768
#define DD    128
#define HH    4
#define HD    32
#define LL    3
#define DFF   2048
#define INDIM 64
#define QKSCALE 0.17677669529663687f

typedef unsigned short u16;
typedef short bf16x8 __attribute__((ext_vector_type(8)));   // 8 bf16 (4 VGPRs)
typedef float f32x4 __attribute__((ext_vector_type(4)));

__device__ __forceinline__ float bf2f(u16 v){
  unsigned u = ((unsigned)v) << 16; float f; __builtin_memcpy(&f, &u, 4); return f;
}
__device__ __forceinline__ u16 f2bf(float f){
  unsigned u; __builtin_memcpy(&u, &f, 4);
  unsigned lsb = (u >> 16) & 1u;
  u += 0x7fffu + lsb;              // round-to-nearest-even
  return (u16)(u >> 16);
}

// ---------------- workspace layout (bytes) ----------------
constexpr size_t OFF_FLAG   = 0;
constexpr size_t OFF_STARTS = 256;
constexpr size_t OFF_BIN    = 1024;
constexpr size_t OFF_BQKV   = OFF_BIN   + 128*4;
constexpr size_t OFF_BO     = OFF_BQKV  + 1152*4;
constexpr size_t OFF_B1     = OFF_BO    + 384*4;
constexpr size_t OFF_B2     = OFF_B1    + 6144*4;
constexpr size_t OFF_LN1G   = OFF_B2    + 384*4;
constexpr size_t OFF_LN1B   = OFF_LN1G  + 384*4;
constexpr size_t OFF_LN2G   = OFF_LN1B  + 384*4;
constexpr size_t OFF_LN2B   = OFF_LN2G  + 384*4;
constexpr size_t OFF_XB     = 40960;
constexpr size_t OFF_WINB   = OFF_XB    + (size_t)2097152*2;
constexpr size_t OFF_WQKVB  = OFF_WINB  + (size_t)8192*2;
constexpr size_t OFF_WOB    = OFF_WQKVB + (size_t)147456*2;
constexpr size_t OFF_W1B    = OFF_WOB   + (size_t)49152*2;
constexpr size_t OFF_W2B    = OFF_W1B   + (size_t)786432*2;
constexpr size_t OFF_CUR    = OFF_W2B   + (size_t)786432*2;
constexpr size_t OFF_TMP    = OFF_CUR   + (size_t)4194304*4;
constexpr size_t OFF_CURB   = OFF_TMP   + (size_t)4194304*4;
constexpr size_t OFF_QKVB   = OFF_CURB  + (size_t)4194304*2;
constexpr size_t OFF_ATTNOB = OFF_QKVB  + (size_t)12582912*2;
constexpr size_t OFF_ACTB   = OFF_ATTNOB+ (size_t)4194304*2;     // (unused now)
constexpr size_t OFF_MASK   = OFF_ACTB  + (size_t)16777216*2;
constexpr size_t OFF_VT     = OFF_MASK  + (size_t)NTOT*4;
constexpr size_t OFF_RED    = OFF_VT    + (size_t)4096*1024*2;
constexpr size_t OFF_CNT    = OFF_RED   + (size_t)32*8*128*4;

// ---------------- dtype detection ----------------
__device__ __forceinline__ int plaus(unsigned bits){
  if ((bits << 1) == 0u) return 1;
  unsigned e = (bits >> 23) & 0xFFu;
  return (e >= 100u && e <= 140u) ? 1 : 0;
}
__global__ void detect_kernel(const unsigned* __restrict__ x, int* __restrict__ flag){
  __shared__ int red[256];
  int t = threadIdx.x, c = 0;
  for (int i = t; i < 2048; i += 256){
    unsigned w = x[i];
    c += (plaus(w << 16) & plaus(w & 0xFFFF0000u));
  }
  red[t] = c; __syncthreads();
  for (int s = 128; s > 0; s >>= 1){ if (t < s) red[t] += red[t+s]; __syncthreads(); }
  if (t == 0) *flag = (red[0] >= 1229) ? 1 : 0;
}

__global__ void conv2bf16_kernel(const void* __restrict__ src, u16* __restrict__ dst,
                                 int n, const int* __restrict__ flag){
  int isb = *flag;
  for (int i = blockIdx.x*blockDim.x + threadIdx.x; i < n; i += gridDim.x*blockDim.x){
    if (isb) dst[i] = ((const u16*)src)[i];
    else     dst[i] = f2bf(((const float*)src)[i]);
  }
}
__global__ void conv2f32_kernel(const void* __restrict__ src, float* __restrict__ dst,
                                int n, const int* __restrict__ flag){
  int isb = *flag;
  for (int i = blockIdx.x*blockDim.x + threadIdx.x; i < n; i += gridDim.x*blockDim.x){
    dst[i] = isb ? bf2f(((const u16*)src)[i]) : ((const float*)src)[i];
  }
}

__global__ void starts_kernel(const int* __restrict__ batch, int* __restrict__ starts){
  int b = threadIdx.x;
  if (b < BB){
    int lo = 0, hi = NTOT;
    while (lo < hi){ int mid = (lo + hi) >> 1; if (batch[mid] < b) lo = mid + 1; else hi = mid; }
    starts[b] = lo;
  }
}

// ---------------- legacy small GEMM (input projection only) ----------------
__global__ __launch_bounds__(256) void gemm_bf16(
    const u16* __restrict__ A, int lda,
    const u16* __restrict__ W, int ldw,
    const float* __restrict__ bias,
    float* __restrict__ Cf, u16* __restrict__ Cb,
    int N, int K, int flags)
{
  __shared__ __align__(16) u16 At[64][32];
  __shared__ __align__(16) u16 Wt[64][32];
  const int t = threadIdx.x;
  const int m0 = blockIdx.x * 64, n0 = blockIdx.y * 64;
  const int wave = t >> 6, lane = t & 63;
  const int quad = lane >> 4, l16 = lane & 15;
  const int lr = t >> 2, lc = (t & 3) * 8;

  f32x4 acc[4];
  #pragma unroll
  for (int i = 0; i < 4; ++i){ acc[i][0]=0.f; acc[i][1]=0.f; acc[i][2]=0.f; acc[i][3]=0.f; }

  const u16* Arow = A + (size_t)(m0 + lr) * lda + lc;
  const u16* Wrow = W + (size_t)(n0 + lr) * ldw + lc;

  for (int k0 = 0; k0 < K; k0 += 32){
    uint4 av = *(const uint4*)(Arow + k0);
    uint4 wv = *(const uint4*)(Wrow + k0);
    __syncthreads();
    *(uint4*)&At[lr][lc] = av;
    *(uint4*)&Wt[lr][lc] = wv;
    __syncthreads();
    bf16x8 af = *(const bf16x8*)&At[wave*16 + l16][quad*8];
    #pragma unroll
    for (int nt = 0; nt < 4; ++nt){
      bf16x8 wf = *(const bf16x8*)&Wt[nt*16 + l16][quad*8];
      acc[nt] = __builtin_amdgcn_mfma_f32_16x16x32_bf16(af, wf, acc[nt], 0, 0, 0);
    }
  }
  const int row = m0 + wave*16 + quad*4;
  #pragma unroll
  for (int nt = 0; nt < 4; ++nt){
    const int col = n0 + nt*16 + l16;
    const float bv = bias ? bias[col] : 0.f;
    #pragma unroll
    for (int r = 0; r < 4; ++r){
      size_t idx = (size_t)(row + r) * N + col;
      float v = acc[nt][r] + bv;
      if (flags & 1) v = fmaxf(v, 0.f);
      if (Cf) Cf[idx] = v;
      if (Cb) Cb[idx] = f2bf(v);
    }
  }
}

// ---------------- scatter projected nodes into padded layout + mask ----------------
__global__ __launch_bounds__(128) void scatter_kernel(
    const float* __restrict__ hlin, const int* __restrict__ batch,
    const int* __restrict__ starts, float* __restrict__ cur,
    u16* __restrict__ curb, float* __restrict__ mask)
{
  int i = blockIdx.x, t = threadIdx.x;
  int g = batch[i];
  int p = i - starts[g];
  float v = hlin[(size_t)i*DD + t];
  float s = v;
  #pragma unroll
  for (int off = 32; off; off >>= 1) s += __shfl_xor(s, off);
  __shared__ float sh[2];
  if ((t & 63) == 0) sh[t >> 6] = s;
  __syncthreads();
  float rowsum = sh[0] + sh[1];
  if ((unsigned)p < (unsigned)NPER && (unsigned)g < (unsigned)BB){
    size_t j = (size_t)g*NPER + p;
    cur[j*DD + t]  = v;
    curb[j*DD + t] = f2bf(v);
    if (t == 0) mask[j] = (rowsum != 0.f) ? 1.f : 0.f;
  }
}

// ---------------- V transpose ----------------
__global__ __launch_bounds__(256) void vtrans_kernel(const u16* __restrict__ qkvb,
                                                     u16* __restrict__ vt)
{
  __shared__ u16 tile[64][33];
  const int t = threadIdx.x;
  const int s0 = blockIdx.x * 64, h = blockIdx.y, b = blockIdx.z;
  {
    int s = t >> 2, dc = (t & 3) * 8;
    uint4 v = *(const uint4*)(qkvb + (size_t)(b*NPER + s0 + s)*384 + 256 + h*HD + dc);
    u16 tmp[8]; __builtin_memcpy(tmp, &v, 16);
    #pragma unroll
    for (int j = 0; j < 8; ++j) tile[s][dc + j] = tmp[j];
  }
  __syncthreads();
  {
    int d = t >> 3, sc = (t & 7) * 8;
    u16 o[8];
    #pragma unroll
    for (int j = 0; j < 8; ++j) o[j] = tile[sc + j][d];
    uint4 ov; __builtin_memcpy(&ov, o, 16);
    *(uint4*)(vt + (size_t)((b*HH + h)*HD + d)*NPER + s0 + sc) = ov;
  }
}

// ---------------- MFMA flash attention ----------------
__global__ __launch_bounds__(256) void fattn_kernel(
    const u16* __restrict__ qkvb, const u16* __restrict__ vt,
    u16* __restrict__ attnob)
{
  __shared__ __align__(16) u16 Klds[64*40];
  __shared__ __align__(16) u16 Vtl[32*72];
  __shared__ __align__(16) u16 Plds[4][16*72];

  const int t = threadIdx.x;
  const int wave = t >> 6, lane = t & 63;
  const int quad = lane >> 4, l16 = lane & 15;
  const int q0 = blockIdx.x * 64;
  const int h = blockIdx.y, b = blockIdx.z;
  const size_t qkvbase = (size_t)b * NPER * 384;

  bf16x8 qf;
  {
    const u16* qp = qkvb + qkvbase + (size_t)(q0 + wave*16 + l16)*384 + h*HD + quad*8;
    uint4 qv = *(const uint4*)qp;
    u16 raw[8]; __builtin_memcpy(raw, &qv, 16);
    #pragma unroll
    for (int j = 0; j < 8; ++j) qf[j] = (short)f2bf(bf2f(raw[j]) * QKSCALE);
  }

  float lsum[4] = {0.f, 0.f, 0.f, 0.f};
  f32x4 o0 = {0.f,0.f,0.f,0.f}, o1 = {0.f,0.f,0.f,0.f};
  u16* pw = &Plds[wave][0];

  const int ks = t >> 2,  kdc = (t & 3) * 8;
  const int vd = t >> 3,  vsc = (t & 7) * 8;

  for (int kt = 0; kt < 16; ++kt){
    __syncthreads();
    {
      uint4 kv = *(const uint4*)(qkvb + qkvbase + (size_t)(kt*64 + ks)*384 + 128 + h*HD + kdc);
      *(uint4*)&Klds[ks*40 + kdc] = kv;
      uint4 vv = *(const uint4*)(vt + (size_t)((b*HH + h)*HD + vd)*NPER + kt*64 + vsc);
      *(uint4*)&Vtl[vd*72 + vsc] = vv;
    }
    __syncthreads();

    f32x4 sfr[4];
    #pragma unroll
    for (int nt = 0; nt < 4; ++nt){
      bf16x8 kf = *(const bf16x8*)&Klds[(nt*16 + l16)*40 + quad*8];
      f32x4 z = {0.f,0.f,0.f,0.f};
      sfr[nt] = __builtin_amdgcn_mfma_f32_16x16x32_bf16(qf, kf, z, 0, 0, 0);
    }

    float psum[4] = {0.f, 0.f, 0.f, 0.f};
    #pragma unroll
    for (int nt = 0; nt < 4; ++nt){
      #pragma unroll
      for (int r = 0; r < 4; ++r){
        float e = __expf(sfr[nt][r]);
        psum[r] += e;
        pw[(quad*4 + r)*72 + nt*16 + l16] = f2bf(e);
      }
    }
    #pragma unroll
    for (int r = 0; r < 4; ++r){
      float s = psum[r];
      s += __shfl_xor(s, 1); s += __shfl_xor(s, 2);
      s += __shfl_xor(s, 4); s += __shfl_xor(s, 8);
      lsum[r] += s;
    }
    __syncthreads();

    #pragma unroll
    for (int c = 0; c < 2; ++c){
      bf16x8 pf = *(const bf16x8*)&pw[l16*72 + c*32 + quad*8];
      bf16x8 v0 = *(const bf16x8*)&Vtl[(l16     )*72 + c*32 + quad*8];
      bf16x8 v1 = *(const bf16x8*)&Vtl[(16 + l16)*72 + c*32 + quad*8];
      o0 = __builtin_amdgcn_mfma_f32_16x16x32_bf16(pf, v0, o0, 0, 0, 0);
      o1 = __builtin_amdgcn_mfma_f32_16x16x32_bf16(pf, v1, o1, 0, 0, 0);
    }
  }

  #pragma unroll
  for (int r = 0; r < 4; ++r){
    float inv = 1.f / lsum[r];
    int row = q0 + wave*16 + quad*4 + r;
    size_t base = (size_t)(b*NPER + row)*DD + h*HD;
    attnob[base + l16]      = f2bf(o0[r] * inv);
    attnob[base + 16 + l16] = f2bf(o1[r] * inv);
  }
}

// ---------------- LN epilogue (wave owns 16 rows): out = LN(resid + O + bias) ----------------
__device__ __forceinline__ void epilogue_ln64(
    const f32x4 O[8], int m0, int wave, int quad, int l16,
    const float* __restrict__ bias, const float* __restrict__ g,
    const float* __restrict__ beta, float* __restrict__ cur,
    u16* __restrict__ curb)
{
  #pragma unroll
  for (int rr = 0; rr < 4; ++rr){
    int row = m0 + wave*16 + quad*4 + rr;
    float vs[8], sum = 0.f;
    #pragma unroll
    for (int nt = 0; nt < 8; ++nt){
      int col = nt*16 + l16;
      float v = O[nt][rr] + bias[col] + cur[(size_t)row*DD + col];
      vs[nt] = v; sum += v;
    }
    sum += __shfl_xor(sum, 1); sum += __shfl_xor(sum, 2);
    sum += __shfl_xor(sum, 4); sum += __shfl_xor(sum, 8);
    float mean = sum * (1.f/DD);
    float sq = 0.f;
    #pragma unroll
    for (int nt = 0; nt < 8; ++nt){ float d = vs[nt] - mean; sq += d*d; }
    sq += __shfl_xor(sq, 1); sq += __shfl_xor(sq, 2);
    sq += __shfl_xor(sq, 4); sq += __shfl_xor(sq, 8);
    float rs = rsqrtf(sq * (1.f/DD) + 1e-5f);
    #pragma unroll
    for (int nt = 0; nt < 8; ++nt){
      int col = nt*16 + l16;
      float o = (vs[nt] - mean)*rs*g[col] + beta[col];
      cur[(size_t)row*DD + col]  = o;
      curb[(size_t)row*DD + col] = f2bf(o);
    }
  }
}

// ---------------- 64-row-block GEMM, W (128x128 slice) in LDS, A-frags in regs ----------------
// mode 0: outb[row][nb*128+col] = bf16(O + bias)   (QKV; grid.y = N/128 slices)
// mode 1: LN epilogue (Wo + LN1)
__global__ __launch_bounds__(256) void wgemm_kernel(
    const u16* __restrict__ A,        // [M][128] bf16
    const u16* __restrict__ Wbase,    // [gridDim.y*128][128] bf16
    const float* __restrict__ biasb,  // [gridDim.y*128]
    int mode,
    u16* __restrict__ outb, int opitch,
    float* __restrict__ cur, u16* __restrict__ curb,
    const float* __restrict__ g, const float* __restrict__ beta)
{
  __shared__ __align__(16) u16 Wl[16384];          // 128x128, XOR-swizzled chunks
  const int t = threadIdx.x, wave = t >> 6, lane = t & 63;
  const int quad = lane >> 4, l16 = lane & 15;
  const int m0 = blockIdx.x * 64, nb = blockIdx.y;
  const u16* Wsl = Wbase + (size_t)nb * 16384;
  const float* bias = biasb + nb * 128;

  // stage W slice: slot s (16B) -> row r = s>>4, stored chunk = s&15, src chunk = (s&15)^(r&15)
  #pragma unroll
  for (int j = 0; j < 8; ++j){
    int s = t + 256*j;
    int r = s >> 4, cx = (s & 15) ^ (r & 15);
    *(uint4*)&Wl[s*8] = *(const uint4*)(Wsl + (size_t)r*128 + cx*8);
  }
  // A-frags in regs: rows m0 + wave*16 + l16
  bf16x8 af[4];
  #pragma unroll
  for (int kk = 0; kk < 4; ++kk)
    af[kk] = *(const bf16x8*)(A + (size_t)(m0 + wave*16 + l16)*128 + kk*32 + quad*8);
  __syncthreads();

  f32x4 O[8];
  #pragma unroll
  for (int nt = 0; nt < 8; ++nt){ O[nt][0]=0.f; O[nt][1]=0.f; O[nt][2]=0.f; O[nt][3]=0.f; }

  #pragma unroll
  for (int nt = 0; nt < 8; ++nt){
    int row = nt*16 + l16;
    bf16x8 wf[4];
    #pragma unroll
    for (int kk = 0; kk < 4; ++kk)
      wf[kk] = *(const bf16x8*)&Wl[(row*16 + ((kk*4 + quad) ^ l16))*8];
    #pragma unroll
    for (int kk = 0; kk < 4; ++kk)
      O[nt] = __builtin_amdgcn_mfma_f32_16x16x32_bf16(af[kk], wf[kk], O[nt], 0, 0, 0);
  }

  if (mode == 0){
    #pragma unroll
    for (int rr = 0; rr < 4; ++rr){
      int row = m0 + wave*16 + quad*4 + rr;
      #pragma unroll
      for (int nt = 0; nt < 8; ++nt){
        int col = nt*16 + l16;
        outb[(size_t)row*opitch + nb*128 + col] = f2bf(O[nt][rr] + bias[col]);
      }
    }
  } else {
    epilogue_ln64(O, m0, wave, quad, l16, bias, g, beta, cur, curb);
  }
}

// ---------------- fused FFN, 64-row blocks, double-buffered W LDS ----------------
// O = relu(A@W1^T+b1)@W2^T + b2; out = LN2(cur + O)
// __launch_bounds__(256, 2): 2 waves/EU = 2 blocks/CU (matches LDS limit) and a
// 256-VGPR budget so the w1r/w2r prefetch regs do NOT spill to scratch
// (R4: VGPR capped at 96 -> ~125 MB/dispatch scratch write traffic, HBM-bound).
__global__ __launch_bounds__(256, 2) void ffn_kernel(
    const u16* __restrict__ Ag,       // CURB [M][128]
    const u16* __restrict__ W1g,      // [2048][128]
    const u16* __restrict__ W2g,      // [128][2048]
    const float* __restrict__ b1,
    const float* __restrict__ b2,
    const float* __restrict__ g, const float* __restrict__ beta,
    float* __restrict__ cur, u16* __restrict__ curb)
{
  __shared__ __align__(16) u16 W1l[2][8192];       // 64x128 chunk, swizzled, x2 buf
  __shared__ __align__(16) u16 W2l[2][8192];       // 128x64 chunk, swizzled, x2 buf
  __shared__ __align__(16) u16 Pl[4][16*72];       // per-wave act, pitch 72

  const int t = threadIdx.x, wave = t >> 6, lane = t & 63;
  const int quad = lane >> 4, l16 = lane & 15;
  const int m0 = blockIdx.x * 64;
  u16* Pw = &Pl[wave][0];

  // A-frags in regs (wave owns 16 rows)
  bf16x8 af[4];
  #pragma unroll
  for (int kk = 0; kk < 4; ++kk)
    af[kk] = *(const bf16x8*)(Ag + (size_t)(m0 + wave*16 + l16)*128 + kk*32 + quad*8);

  f32x4 O[8];
  #pragma unroll
  for (int nt = 0; nt < 8; ++nt){ O[nt][0]=0.f; O[nt][1]=0.f; O[nt][2]=0.f; O[nt][3]=0.f; }

  uint4 w1r[4], w2r[4];
  auto ldW = [&](int dffc){
    #pragma unroll
    for (int j = 0; j < 4; ++j){
      int s = t + 256*j;
      { int r = s >> 4, cx = (s & 15) ^ (r & 15);
        w1r[j] = *(const uint4*)(W1g + (size_t)(dffc + r)*128 + cx*8); }
      { int r = s >> 3, cx = (s & 7) ^ (r & 7);
        w2r[j] = *(const uint4*)(W2g + (size_t)r*DFF + dffc + cx*8); }
    }
  };

  // prologue: chunk 0 -> buf 0
  ldW(0);
  #pragma unroll
  for (int j = 0; j < 4; ++j){
    *(uint4*)&W1l[0][(t + 256*j)*8] = w1r[j];
    *(uint4*)&W2l[0][(t + 256*j)*8] = w2r[j];
  }
  __syncthreads();

  for (int c = 0; c < 32; ++c){
    const int buf = c & 1;
    if (c + 1 < 32) ldW((c + 1)*64);               // loads in flight across compute

    // phase 1: act = relu(A @ W1c^T + b1) -> P (wave-private, bf16)
    #pragma unroll
    for (int nt = 0; nt < 4; ++nt){
      int row = nt*16 + l16;                       // dff-local row
      bf16x8 wf[4];
      #pragma unroll
      for (int kk = 0; kk < 4; ++kk)
        wf[kk] = *(const bf16x8*)&W1l[buf][(row*16 + ((kk*4 + quad) ^ l16))*8];
      float b1v = b1[c*64 + row];
      f32x4 s = {0.f,0.f,0.f,0.f};
      #pragma unroll
      for (int kk = 0; kk < 4; ++kk)
        s = __builtin_amdgcn_mfma_f32_16x16x32_bf16(af[kk], wf[kk], s, 0, 0, 0);
      #pragma unroll
      for (int rr = 0; rr < 4; ++rr)
        Pw[(quad*4 + rr)*72 + nt*16 + l16] = f2bf(fmaxf(s[rr] + b1v, 0.f));
    }
    // wave-internal LDS RAW: drain before cross-lane read
    asm volatile("s_waitcnt lgkmcnt(0)" ::: "memory");

    // phase 2: O += P @ W2c^T
    bf16x8 pf[2];
    #pragma unroll
    for (int kk = 0; kk < 2; ++kk)
      pf[kk] = *(const bf16x8*)&Pw[l16*72 + kk*32 + quad*8];
    #pragma unroll
    for (int nt = 0; nt < 8; ++nt){
      int row = nt*16 + l16;                       // output-col row of W2
      bf16x8 wf[2];
      #pragma unroll
      for (int kk = 0; kk < 2; ++kk)
        wf[kk] = *(const bf16x8*)&W2l[buf][(row*8 + ((kk*4 + quad) ^ (l16 & 7)))*8];
      #pragma unroll
      for (int kk = 0; kk < 2; ++kk)
        O[nt] = __builtin_amdgcn_mfma_f32_16x16x32_bf16(pf[kk], wf[kk], O[nt], 0, 0, 0);
    }

    // stage chunk c+1 into the other buffer; single barrier per chunk
    if (c + 1 < 32){
      #pragma unroll
      for (int j = 0; j < 4; ++j){
        *(uint4*)&W1l[buf ^ 1][(t + 256*j)*8] = w1r[j];
        *(uint4*)&W2l[buf ^ 1][(t + 256*j)*8] = w2r[j];
      }
      __syncthreads();
    }
  }

  epilogue_ln64(O, m0, wave, quad, l16, b2, g, beta, cur, curb);
}

// ---------------- final masked mean, two-stage ----------------
__global__ __launch_bounds__(128) void reduce1_kernel(
    const float* __restrict__ cur, const float* __restrict__ mask,
    float* __restrict__ partial, float* __restrict__ cnt)
{
  int b = blockIdx.x, c = blockIdx.y, t = threadIdx.x;
  float acc = 0.f, cn = 0.f;
  for (int s = c*128; s < c*128 + 128; ++s){
    float mk = mask[b*NPER + s];
    acc += cur[(size_t)(b*NPER + s)*DD + t] * mk;
    cn += mk;
  }
  partial[(size_t)(b*8 + c)*DD + t] = acc;
  if (t == 0) cnt[b*8 + c] = cn;
}
__global__ __launch_bounds__(128) void reduce2_kernel(
    const float* __restrict__ partial, const float* __restrict__ cnt,
    const int* __restrict__ flag, void* __restrict__ out)
{
  int b = blockIdx.x, t = threadIdx.x;
  float acc = 0.f, cn = 0.f;
  #pragma unroll
  for (int c = 0; c < 8; ++c){
    acc += partial[(size_t)(b*8 + c)*DD + t];
    cn  += cnt[b*8 + c];
  }
  float val = acc / cn;
  if (*flag) ((u16*)out)[b*DD + t] = f2bf(val);
  else       ((float*)out)[b*DD + t] = val;
}

// ---------------- host ----------------
extern "C" void kernel_launch(void* const* d_in, const int* in_sizes, int n_in,
                              void* d_out, int out_size, void* d_ws, size_t ws_size,
                              hipStream_t stream)
{
  (void)in_sizes; (void)n_in; (void)out_size; (void)ws_size;
  char* ws = (char*)d_ws;
  int*   flag   = (int*)(ws + OFF_FLAG);
  int*   starts = (int*)(ws + OFF_STARTS);
  float* BIN  = (float*)(ws + OFF_BIN);
  float* BQKV = (float*)(ws + OFF_BQKV);
  float* BO   = (float*)(ws + OFF_BO);
  float* B1   = (float*)(ws + OFF_B1);
  float* B2   = (float*)(ws + OFF_B2);
  float* LN1G = (float*)(ws + OFF_LN1G);
  float* LN1B = (float*)(ws + OFF_LN1B);
  float* LN2G = (float*)(ws + OFF_LN2G);
  float* LN2B = (float*)(ws + OFF_LN2B);
  u16* XB    = (u16*)(ws + OFF_XB);
  u16* WINB  = (u16*)(ws + OFF_WINB);
  u16* WQKVB = (u16*)(ws + OFF_WQKVB);
  u16* WOB   = (u16*)(ws + OFF_WOB);
  u16* W1B   = (u16*)(ws + OFF_W1B);
  u16* W2B   = (u16*)(ws + OFF_W2B);
  float* CUR = (float*)(ws + OFF_CUR);
  float* TMP = (float*)(ws + OFF_TMP);
  u16* CURB  = (u16*)(ws + OFF_CURB);
  u16* QKVB  = (u16*)(ws + OFF_QKVB);
  u16* ATTNOB= (u16*)(ws + OFF_ATTNOB);
  float* MASK= (float*)(ws + OFF_MASK);
  u16* VT    = (u16*)(ws + OFF_VT);
  float* RED = (float*)(ws + OFF_RED);
  float* CNT = (float*)(ws + OFF_CNT);

  detect_kernel<<<1, 256, 0, stream>>>((const unsigned*)d_in[0], flag);
  starts_kernel<<<1, 64, 0, stream>>>((const int*)d_in[1], starts);

  auto cb = [&](const void* s, u16* dp, int n){
    conv2bf16_kernel<<<(n + 1023)/1024, 256, 0, stream>>>(s, dp, n, flag);
  };
  auto cf = [&](const void* s, float* dp, int n){
    conv2f32_kernel<<<(n + 1023)/1024, 256, 0, stream>>>(s, dp, n, flag);
  };
  cb(d_in[0],  XB,    NTOT*INDIM);
  cb(d_in[2],  WINB,  DD*INDIM);
  cb(d_in[4],  WQKVB, LL*3*DD*DD);
  cb(d_in[6],  WOB,   LL*DD*DD);
  cb(d_in[8],  W1B,   LL*DFF*DD);
  cb(d_in[10], W2B,   LL*DD*DFF);
  cf(d_in[3],  BIN,   DD);
  cf(d_in[5],  BQKV,  LL*3*DD);
  cf(d_in[7],  BO,    LL*DD);
  cf(d_in[9],  B1,    LL*DFF);
  cf(d_in[11], B2,    LL*DD);
  cf(d_in[12], LN1G,  LL*DD);
  cf(d_in[13], LN1B,  LL*DD);
  cf(d_in[14], LN2G,  LL*DD);
  cf(d_in[15], LN2B,  LL*DD);

  gemm_bf16<<<dim3(NTOT/64, DD/64), 256, 0, stream>>>(
      XB, INDIM, WINB, INDIM, BIN, TMP, nullptr, DD, INDIM, 0);
  scatter_kernel<<<NTOT, 128, 0, stream>>>(TMP, (const int*)d_in[1], starts, CUR, CURB, MASK);

  for (int l = 0; l < LL; ++l){
    // QKV: 3 N-slices of 128
    wgemm_kernel<<<dim3(NTOT/64, 3), 256, 0, stream>>>(
        CURB, WQKVB + (size_t)l*3*DD*DD, BQKV + l*3*DD, 0,
        QKVB, 384, nullptr, nullptr, nullptr, nullptr);
    vtrans_kernel<<<dim3(NPER/64, HH, BB), 256, 0, stream>>>(QKVB, VT);
    fattn_kernel<<<dim3(NPER/64, HH, BB), 256, 0, stream>>>(QKVB, VT, ATTNOB);
    // Wo + residual + LN1
    wgemm_kernel<<<dim3(NTOT/64, 1), 256, 0, stream>>>(
        ATTNOB, WOB + (size_t)l*DD*DD, BO + l*DD, 1,
        nullptr, 0, CUR, CURB, LN1G + l*DD, LN1B + l*DD);
    // fused FFN + residual + LN2
    ffn_kernel<<<dim3(NTOT/64), 256, 0, stream>>>(
        CURB, W1B + (size_t)l*DFF*DD, W2B + (size_t)l*DD*DFF,
        B1 + l*DFF, B2 + l*DD, LN2G + l*DD, LN2B + l*DD, CUR, CURB);
  }

  reduce1_kernel<<<dim3(BB, 8), 128, 0, stream>>>(CUR, MASK, RED, CNT);
  reduce2_kernel<<<BB, 128, 0, stream>>>(RED, CNT, flag, d_out);
}

// Round 6
// 615.835 us; speedup vs baseline: 1.4374x; 1.4368x over previous
//
#include <hip/hip_runtime.h>
#include <hip/hip_bf16.h>
#include <stdint.h>

// ---------------- static problem sizes ----------------
#define BB    32
#define NPER  1024
#define NTOT  32768
#define DD    128
#define HH    4
#define HD    32
#define LL    3
#define DFF   2048
#define INDIM 64
#define QKSCALE 0.17677669529663687f

typedef unsigned short u16;
typedef short bf16x8 __attribute__((ext_vector_type(8)));   // 8 bf16 (4 VGPRs)
typedef float f32x4 __attribute__((ext_vector_type(4)));

// address-space casts for global_load_lds (direct global->LDS DMA)
#define AS_GLOBAL(p) ((const __attribute__((address_space(1))) void*)(p))
#define AS_LDS(p)    ((__attribute__((address_space(3))) void*)(p))

__device__ __forceinline__ float bf2f(u16 v){
  unsigned u = ((unsigned)v) << 16; float f; __builtin_memcpy(&f, &u, 4); return f;
}
__device__ __forceinline__ u16 f2bf(float f){
  unsigned u; __builtin_memcpy(&u, &f, 4);
  unsigned lsb = (u >> 16) & 1u;
  u += 0x7fffu + lsb;              // round-to-nearest-even
  return (u16)(u >> 16);
}

// ---------------- workspace layout (bytes) ----------------
constexpr size_t OFF_FLAG   = 0;
constexpr size_t OFF_STARTS = 256;
constexpr size_t OFF_BIN    = 1024;
constexpr size_t OFF_BQKV   = OFF_BIN   + 128*4;
constexpr size_t OFF_BO     = OFF_BQKV  + 1152*4;
constexpr size_t OFF_B1     = OFF_BO    + 384*4;
constexpr size_t OFF_B2     = OFF_B1    + 6144*4;
constexpr size_t OFF_LN1G   = OFF_B2    + 384*4;
constexpr size_t OFF_LN1B   = OFF_LN1G  + 384*4;
constexpr size_t OFF_LN2G   = OFF_LN1B  + 384*4;
constexpr size_t OFF_LN2B   = OFF_LN2G  + 384*4;
constexpr size_t OFF_XB     = 40960;
constexpr size_t OFF_WINB   = OFF_XB    + (size_t)2097152*2;
constexpr size_t OFF_WQKVB  = OFF_WINB  + (size_t)8192*2;
constexpr size_t OFF_WOB    = OFF_WQKVB + (size_t)147456*2;
constexpr size_t OFF_W1B    = OFF_WOB   + (size_t)49152*2;
constexpr size_t OFF_W2B    = OFF_W1B   + (size_t)786432*2;
constexpr size_t OFF_CUR    = OFF_W2B   + (size_t)786432*2;
constexpr size_t OFF_TMP    = OFF_CUR   + (size_t)4194304*4;
constexpr size_t OFF_CURB   = OFF_TMP   + (size_t)4194304*4;
constexpr size_t OFF_QKVB   = OFF_CURB  + (size_t)4194304*2;
constexpr size_t OFF_ATTNOB = OFF_QKVB  + (size_t)12582912*2;
constexpr size_t OFF_ACTB   = OFF_ATTNOB+ (size_t)4194304*2;     // (unused now)
constexpr size_t OFF_MASK   = OFF_ACTB  + (size_t)16777216*2;
constexpr size_t OFF_VT     = OFF_MASK  + (size_t)NTOT*4;
constexpr size_t OFF_RED    = OFF_VT    + (size_t)4096*1024*2;
constexpr size_t OFF_CNT    = OFF_RED   + (size_t)32*8*128*4;

// ---------------- dtype detection ----------------
__device__ __forceinline__ int plaus(unsigned bits){
  if ((bits << 1) == 0u) return 1;
  unsigned e = (bits >> 23) & 0xFFu;
  return (e >= 100u && e <= 140u) ? 1 : 0;
}
__global__ void detect_kernel(const unsigned* __restrict__ x, int* __restrict__ flag){
  __shared__ int red[256];
  int t = threadIdx.x, c = 0;
  for (int i = t; i < 2048; i += 256){
    unsigned w = x[i];
    c += (plaus(w << 16) & plaus(w & 0xFFFF0000u));
  }
  red[t] = c; __syncthreads();
  for (int s = 128; s > 0; s >>= 1){ if (t < s) red[t] += red[t+s]; __syncthreads(); }
  if (t == 0) *flag = (red[0] >= 1229) ? 1 : 0;
}

__global__ void conv2bf16_kernel(const void* __restrict__ src, u16* __restrict__ dst,
                                 int n, const int* __restrict__ flag){
  int isb = *flag;
  for (int i = blockIdx.x*blockDim.x + threadIdx.x; i < n; i += gridDim.x*blockDim.x){
    if (isb) dst[i] = ((const u16*)src)[i];
    else     dst[i] = f2bf(((const float*)src)[i]);
  }
}
__global__ void conv2f32_kernel(const void* __restrict__ src, float* __restrict__ dst,
                                int n, const int* __restrict__ flag){
  int isb = *flag;
  for (int i = blockIdx.x*blockDim.x + threadIdx.x; i < n; i += gridDim.x*blockDim.x){
    dst[i] = isb ? bf2f(((const u16*)src)[i]) : ((const float*)src)[i];
  }
}

__global__ void starts_kernel(const int* __restrict__ batch, int* __restrict__ starts){
  int b = threadIdx.x;
  if (b < BB){
    int lo = 0, hi = NTOT;
    while (lo < hi){ int mid = (lo + hi) >> 1; if (batch[mid] < b) lo = mid + 1; else hi = mid; }
    starts[b] = lo;
  }
}

// ---------------- legacy small GEMM (input projection only) ----------------
__global__ __launch_bounds__(256) void gemm_bf16(
    const u16* __restrict__ A, int lda,
    const u16* __restrict__ W, int ldw,
    const float* __restrict__ bias,
    float* __restrict__ Cf, u16* __restrict__ Cb,
    int N, int K, int flags)
{
  __shared__ __align__(16) u16 At[64][32];
  __shared__ __align__(16) u16 Wt[64][32];
  const int t = threadIdx.x;
  const int m0 = blockIdx.x * 64, n0 = blockIdx.y * 64;
  const int wave = t >> 6, lane = t & 63;
  const int quad = lane >> 4, l16 = lane & 15;
  const int lr = t >> 2, lc = (t & 3) * 8;

  f32x4 acc[4];
  #pragma unroll
  for (int i = 0; i < 4; ++i){ acc[i][0]=0.f; acc[i][1]=0.f; acc[i][2]=0.f; acc[i][3]=0.f; }

  const u16* Arow = A + (size_t)(m0 + lr) * lda + lc;
  const u16* Wrow = W + (size_t)(n0 + lr) * ldw + lc;

  for (int k0 = 0; k0 < K; k0 += 32){
    uint4 av = *(const uint4*)(Arow + k0);
    uint4 wv = *(const uint4*)(Wrow + k0);
    __syncthreads();
    *(uint4*)&At[lr][lc] = av;
    *(uint4*)&Wt[lr][lc] = wv;
    __syncthreads();
    bf16x8 af = *(const bf16x8*)&At[wave*16 + l16][quad*8];
    #pragma unroll
    for (int nt = 0; nt < 4; ++nt){
      bf16x8 wf = *(const bf16x8*)&Wt[nt*16 + l16][quad*8];
      acc[nt] = __builtin_amdgcn_mfma_f32_16x16x32_bf16(af, wf, acc[nt], 0, 0, 0);
    }
  }
  const int row = m0 + wave*16 + quad*4;
  #pragma unroll
  for (int nt = 0; nt < 4; ++nt){
    const int col = n0 + nt*16 + l16;
    const float bv = bias ? bias[col] : 0.f;
    #pragma unroll
    for (int r = 0; r < 4; ++r){
      size_t idx = (size_t)(row + r) * N + col;
      float v = acc[nt][r] + bv;
      if (flags & 1) v = fmaxf(v, 0.f);
      if (Cf) Cf[idx] = v;
      if (Cb) Cb[idx] = f2bf(v);
    }
  }
}

// ---------------- scatter projected nodes into padded layout + mask ----------------
__global__ __launch_bounds__(128) void scatter_kernel(
    const float* __restrict__ hlin, const int* __restrict__ batch,
    const int* __restrict__ starts, float* __restrict__ cur,
    u16* __restrict__ curb, float* __restrict__ mask)
{
  int i = blockIdx.x, t = threadIdx.x;
  int g = batch[i];
  int p = i - starts[g];
  float v = hlin[(size_t)i*DD + t];
  float s = v;
  #pragma unroll
  for (int off = 32; off; off >>= 1) s += __shfl_xor(s, off);
  __shared__ float sh[2];
  if ((t & 63) == 0) sh[t >> 6] = s;
  __syncthreads();
  float rowsum = sh[0] + sh[1];
  if ((unsigned)p < (unsigned)NPER && (unsigned)g < (unsigned)BB){
    size_t j = (size_t)g*NPER + p;
    cur[j*DD + t]  = v;
    curb[j*DD + t] = f2bf(v);
    if (t == 0) mask[j] = (rowsum != 0.f) ? 1.f : 0.f;
  }
}

// ---------------- V transpose ----------------
__global__ __launch_bounds__(256) void vtrans_kernel(const u16* __restrict__ qkvb,
                                                     u16* __restrict__ vt)
{
  __shared__ u16 tile[64][33];
  const int t = threadIdx.x;
  const int s0 = blockIdx.x * 64, h = blockIdx.y, b = blockIdx.z;
  {
    int s = t >> 2, dc = (t & 3) * 8;
    uint4 v = *(const uint4*)(qkvb + (size_t)(b*NPER + s0 + s)*384 + 256 + h*HD + dc);
    u16 tmp[8]; __builtin_memcpy(tmp, &v, 16);
    #pragma unroll
    for (int j = 0; j < 8; ++j) tile[s][dc + j] = tmp[j];
  }
  __syncthreads();
  {
    int d = t >> 3, sc = (t & 7) * 8;
    u16 o[8];
    #pragma unroll
    for (int j = 0; j < 8; ++j) o[j] = tile[sc + j][d];
    uint4 ov; __builtin_memcpy(&ov, o, 16);
    *(uint4*)(vt + (size_t)((b*HH + h)*HD + d)*NPER + s0 + sc) = ov;
  }
}

// ---------------- MFMA flash attention ----------------
__global__ __launch_bounds__(256) void fattn_kernel(
    const u16* __restrict__ qkvb, const u16* __restrict__ vt,
    u16* __restrict__ attnob)
{
  __shared__ __align__(16) u16 Klds[64*40];
  __shared__ __align__(16) u16 Vtl[32*72];
  __shared__ __align__(16) u16 Plds[4][16*72];

  const int t = threadIdx.x;
  const int wave = t >> 6, lane = t & 63;
  const int quad = lane >> 4, l16 = lane & 15;
  const int q0 = blockIdx.x * 64;
  const int h = blockIdx.y, b = blockIdx.z;
  const size_t qkvbase = (size_t)b * NPER * 384;

  bf16x8 qf;
  {
    const u16* qp = qkvb + qkvbase + (size_t)(q0 + wave*16 + l16)*384 + h*HD + quad*8;
    uint4 qv = *(const uint4*)qp;
    u16 raw[8]; __builtin_memcpy(raw, &qv, 16);
    #pragma unroll
    for (int j = 0; j < 8; ++j) qf[j] = (short)f2bf(bf2f(raw[j]) * QKSCALE);
  }

  float lsum[4] = {0.f, 0.f, 0.f, 0.f};
  f32x4 o0 = {0.f,0.f,0.f,0.f}, o1 = {0.f,0.f,0.f,0.f};
  u16* pw = &Plds[wave][0];

  const int ks = t >> 2,  kdc = (t & 3) * 8;
  const int vd = t >> 3,  vsc = (t & 7) * 8;

  for (int kt = 0; kt < 16; ++kt){
    __syncthreads();
    {
      uint4 kv = *(const uint4*)(qkvb + qkvbase + (size_t)(kt*64 + ks)*384 + 128 + h*HD + kdc);
      *(uint4*)&Klds[ks*40 + kdc] = kv;
      uint4 vv = *(const uint4*)(vt + (size_t)((b*HH + h)*HD + vd)*NPER + kt*64 + vsc);
      *(uint4*)&Vtl[vd*72 + vsc] = vv;
    }
    __syncthreads();

    f32x4 sfr[4];
    #pragma unroll
    for (int nt = 0; nt < 4; ++nt){
      bf16x8 kf = *(const bf16x8*)&Klds[(nt*16 + l16)*40 + quad*8];
      f32x4 z = {0.f,0.f,0.f,0.f};
      sfr[nt] = __builtin_amdgcn_mfma_f32_16x16x32_bf16(qf, kf, z, 0, 0, 0);
    }

    float psum[4] = {0.f, 0.f, 0.f, 0.f};
    #pragma unroll
    for (int nt = 0; nt < 4; ++nt){
      #pragma unroll
      for (int r = 0; r < 4; ++r){
        float e = __expf(sfr[nt][r]);
        psum[r] += e;
        pw[(quad*4 + r)*72 + nt*16 + l16] = f2bf(e);
      }
    }
    #pragma unroll
    for (int r = 0; r < 4; ++r){
      float s = psum[r];
      s += __shfl_xor(s, 1); s += __shfl_xor(s, 2);
      s += __shfl_xor(s, 4); s += __shfl_xor(s, 8);
      lsum[r] += s;
    }
    __syncthreads();

    #pragma unroll
    for (int c = 0; c < 2; ++c){
      bf16x8 pf = *(const bf16x8*)&pw[l16*72 + c*32 + quad*8];
      bf16x8 v0 = *(const bf16x8*)&Vtl[(l16     )*72 + c*32 + quad*8];
      bf16x8 v1 = *(const bf16x8*)&Vtl[(16 + l16)*72 + c*32 + quad*8];
      o0 = __builtin_amdgcn_mfma_f32_16x16x32_bf16(pf, v0, o0, 0, 0, 0);
      o1 = __builtin_amdgcn_mfma_f32_16x16x32_bf16(pf, v1, o1, 0, 0, 0);
    }
  }

  #pragma unroll
  for (int r = 0; r < 4; ++r){
    float inv = 1.f / lsum[r];
    int row = q0 + wave*16 + quad*4 + r;
    size_t base = (size_t)(b*NPER + row)*DD + h*HD;
    attnob[base + l16]      = f2bf(o0[r] * inv);
    attnob[base + 16 + l16] = f2bf(o1[r] * inv);
  }
}

// ---------------- LN epilogue (wave owns 16 rows): out = LN(resid + O + bias) ----------------
__device__ __forceinline__ void epilogue_ln64(
    const f32x4 O[8], int m0, int wave, int quad, int l16,
    const float* __restrict__ bias, const float* __restrict__ g,
    const float* __restrict__ beta, float* __restrict__ cur,
    u16* __restrict__ curb)
{
  #pragma unroll
  for (int rr = 0; rr < 4; ++rr){
    int row = m0 + wave*16 + quad*4 + rr;
    float vs[8], sum = 0.f;
    #pragma unroll
    for (int nt = 0; nt < 8; ++nt){
      int col = nt*16 + l16;
      float v = O[nt][rr] + bias[col] + cur[(size_t)row*DD + col];
      vs[nt] = v; sum += v;
    }
    sum += __shfl_xor(sum, 1); sum += __shfl_xor(sum, 2);
    sum += __shfl_xor(sum, 4); sum += __shfl_xor(sum, 8);
    float mean = sum * (1.f/DD);
    float sq = 0.f;
    #pragma unroll
    for (int nt = 0; nt < 8; ++nt){ float d = vs[nt] - mean; sq += d*d; }
    sq += __shfl_xor(sq, 1); sq += __shfl_xor(sq, 2);
    sq += __shfl_xor(sq, 4); sq += __shfl_xor(sq, 8);
    float rs = rsqrtf(sq * (1.f/DD) + 1e-5f);
    #pragma unroll
    for (int nt = 0; nt < 8; ++nt){
      int col = nt*16 + l16;
      float o = (vs[nt] - mean)*rs*g[col] + beta[col];
      cur[(size_t)row*DD + col]  = o;
      curb[(size_t)row*DD + col] = f2bf(o);
    }
  }
}

// ---------------- 64-row-block GEMM, W (128x128 slice) in LDS, A-frags in regs ----------------
// mode 0: outb[row][nb*128+col] = bf16(O + bias)   (QKV; grid.y = N/128 slices)
// mode 1: LN epilogue (Wo + LN1)
__global__ __launch_bounds__(256) void wgemm_kernel(
    const u16* __restrict__ A,        // [M][128] bf16
    const u16* __restrict__ Wbase,    // [gridDim.y*128][128] bf16
    const float* __restrict__ biasb,  // [gridDim.y*128]
    int mode,
    u16* __restrict__ outb, int opitch,
    float* __restrict__ cur, u16* __restrict__ curb,
    const float* __restrict__ g, const float* __restrict__ beta)
{
  __shared__ __align__(16) u16 Wl[16384];          // 128x128, XOR-swizzled chunks
  const int t = threadIdx.x, wave = t >> 6, lane = t & 63;
  const int quad = lane >> 4, l16 = lane & 15;
  const int m0 = blockIdx.x * 64, nb = blockIdx.y;
  const u16* Wsl = Wbase + (size_t)nb * 16384;
  const float* bias = biasb + nb * 128;

  // stage W slice: slot s (16B) -> row r = s>>4, stored chunk = s&15, src chunk = (s&15)^(r&15)
  #pragma unroll
  for (int j = 0; j < 8; ++j){
    int s = t + 256*j;
    int r = s >> 4, cx = (s & 15) ^ (r & 15);
    *(uint4*)&Wl[s*8] = *(const uint4*)(Wsl + (size_t)r*128 + cx*8);
  }
  // A-frags in regs: rows m0 + wave*16 + l16
  bf16x8 af[4];
  #pragma unroll
  for (int kk = 0; kk < 4; ++kk)
    af[kk] = *(const bf16x8*)(A + (size_t)(m0 + wave*16 + l16)*128 + kk*32 + quad*8);
  __syncthreads();

  f32x4 O[8];
  #pragma unroll
  for (int nt = 0; nt < 8; ++nt){ O[nt][0]=0.f; O[nt][1]=0.f; O[nt][2]=0.f; O[nt][3]=0.f; }

  #pragma unroll
  for (int nt = 0; nt < 8; ++nt){
    int row = nt*16 + l16;
    bf16x8 wf[4];
    #pragma unroll
    for (int kk = 0; kk < 4; ++kk)
      wf[kk] = *(const bf16x8*)&Wl[(row*16 + ((kk*4 + quad) ^ l16))*8];
    #pragma unroll
    for (int kk = 0; kk < 4; ++kk)
      O[nt] = __builtin_amdgcn_mfma_f32_16x16x32_bf16(af[kk], wf[kk], O[nt], 0, 0, 0);
  }

  if (mode == 0){
    #pragma unroll
    for (int rr = 0; rr < 4; ++rr){
      int row = m0 + wave*16 + quad*4 + rr;
      #pragma unroll
      for (int nt = 0; nt < 8; ++nt){
        int col = nt*16 + l16;
        outb[(size_t)row*opitch + nb*128 + col] = f2bf(O[nt][rr] + bias[col]);
      }
    }
  } else {
    epilogue_ln64(O, m0, wave, quad, l16, bias, g, beta, cur, curb);
  }
}

// ---------------- fused FFN, 64-row blocks, double-buffered W LDS via global_load_lds ----------------
// O = relu(A@W1^T+b1)@W2^T + b2; out = LN2(cur + O)
// Staging uses global->LDS DMA (no staging VGPRs -> nothing to spill; R4/R5's
// register-held prefetch was spilled to scratch: ~150 MB/dispatch HBM writes).
__global__ __launch_bounds__(256, 2) void ffn_kernel(
    const u16* __restrict__ Ag,       // CURB [M][128]
    const u16* __restrict__ W1g,      // [2048][128]
    const u16* __restrict__ W2g,      // [128][2048]
    const float* __restrict__ b1,
    const float* __restrict__ b2,
    const float* __restrict__ g, const float* __restrict__ beta,
    float* __restrict__ cur, u16* __restrict__ curb)
{
  __shared__ __align__(16) u16 W1l[2][8192];       // 64x128 chunk, swizzled, x2 buf
  __shared__ __align__(16) u16 W2l[2][8192];       // 128x64 chunk, swizzled, x2 buf
  __shared__ __align__(16) u16 Pl[4][16*72];       // per-wave act, pitch 72

  const int t = threadIdx.x, wave = t >> 6, lane = t & 63;
  const int quad = lane >> 4, l16 = lane & 15;
  const int m0 = blockIdx.x * 64;
  u16* Pw = &Pl[wave][0];

  // DMA staging: slot s (16B). W1: row r=s>>4, chunk cx=(s&15)^(r&15).
  // W2: row r=s>>3, cx=(s&7)^(r&7). gptr per-lane; LDS dst wave-uniform + lane*16.
  auto stage = [&](int buf, int dffc){
    #pragma unroll
    for (int i = 0; i < 4; ++i){
      const int s0 = wave*256 + i*64;
      const int s  = s0 + lane;
      { int r = s >> 4, cx = (s & 15) ^ (r & 15);
        __builtin_amdgcn_global_load_lds(
            AS_GLOBAL(W1g + (size_t)(dffc + r)*128 + cx*8),
            AS_LDS(&W1l[buf][s0*8]), 16, 0, 0); }
      { int r = s >> 3, cx = (s & 7) ^ (r & 7);
        __builtin_amdgcn_global_load_lds(
            AS_GLOBAL(W2g + (size_t)r*DFF + dffc + cx*8),
            AS_LDS(&W2l[buf][s0*8]), 16, 0, 0); }
    }
  };

  // A-frags in regs (wave owns 16 rows)
  bf16x8 af[4];
  #pragma unroll
  for (int kk = 0; kk < 4; ++kk)
    af[kk] = *(const bf16x8*)(Ag + (size_t)(m0 + wave*16 + l16)*128 + kk*32 + quad*8);

  f32x4 O[8];
  #pragma unroll
  for (int nt = 0; nt < 8; ++nt){ O[nt][0]=0.f; O[nt][1]=0.f; O[nt][2]=0.f; O[nt][3]=0.f; }

  // prologue: chunk 0 -> buf 0
  stage(0, 0);
  asm volatile("s_waitcnt vmcnt(0)" ::: "memory");
  __syncthreads();

  for (int c = 0; c < 32; ++c){
    const int buf = c & 1;
    if (c + 1 < 32) stage(buf ^ 1, (c + 1)*64);    // DMA in flight across compute

    // phase 1: act = relu(A @ W1c^T + b1) -> P (wave-private, bf16)
    #pragma unroll
    for (int nt = 0; nt < 4; ++nt){
      int row = nt*16 + l16;                       // dff-local row
      bf16x8 wf[4];
      #pragma unroll
      for (int kk = 0; kk < 4; ++kk)
        wf[kk] = *(const bf16x8*)&W1l[buf][(row*16 + ((kk*4 + quad) ^ l16))*8];
      float b1v = b1[c*64 + row];
      f32x4 s = {0.f,0.f,0.f,0.f};
      #pragma unroll
      for (int kk = 0; kk < 4; ++kk)
        s = __builtin_amdgcn_mfma_f32_16x16x32_bf16(af[kk], wf[kk], s, 0, 0, 0);
      #pragma unroll
      for (int rr = 0; rr < 4; ++rr)
        Pw[(quad*4 + rr)*72 + nt*16 + l16] = f2bf(fmaxf(s[rr] + b1v, 0.f));
    }
    // wave-internal LDS RAW: drain before cross-lane read
    asm volatile("s_waitcnt lgkmcnt(0)" ::: "memory");

    // phase 2: O += P @ W2c^T
    bf16x8 pf[2];
    #pragma unroll
    for (int kk = 0; kk < 2; ++kk)
      pf[kk] = *(const bf16x8*)&Pw[l16*72 + kk*32 + quad*8];
    #pragma unroll
    for (int nt = 0; nt < 8; ++nt){
      int row = nt*16 + l16;                       // output-col row of W2
      bf16x8 wf[2];
      #pragma unroll
      for (int kk = 0; kk < 2; ++kk)
        wf[kk] = *(const bf16x8*)&W2l[buf][(row*8 + ((kk*4 + quad) ^ (l16 & 7)))*8];
      #pragma unroll
      for (int kk = 0; kk < 2; ++kk)
        O[nt] = __builtin_amdgcn_mfma_f32_16x16x32_bf16(pf[kk], wf[kk], O[nt], 0, 0, 0);
    }

    // wait own DMAs for chunk c+1, then barrier: next iter reads buf^1,
    // and iter c+2's DMA will overwrite buf (all reads of buf done here).
    if (c + 1 < 32){
      asm volatile("s_waitcnt vmcnt(0)" ::: "memory");
      __syncthreads();
    }
  }

  epilogue_ln64(O, m0, wave, quad, l16, b2, g, beta, cur, curb);
}

// ---------------- final masked mean, two-stage ----------------
__global__ __launch_bounds__(128) void reduce1_kernel(
    const float* __restrict__ cur, const float* __restrict__ mask,
    float* __restrict__ partial, float* __restrict__ cnt)
{
  int b = blockIdx.x, c = blockIdx.y, t = threadIdx.x;
  float acc = 0.f, cn = 0.f;
  for (int s = c*128; s < c*128 + 128; ++s){
    float mk = mask[b*NPER + s];
    acc += cur[(size_t)(b*NPER + s)*DD + t] * mk;
    cn += mk;
  }
  partial[(size_t)(b*8 + c)*DD + t] = acc;
  if (t == 0) cnt[b*8 + c] = cn;
}
__global__ __launch_bounds__(128) void reduce2_kernel(
    const float* __restrict__ partial, const float* __restrict__ cnt,
    const int* __restrict__ flag, void* __restrict__ out)
{
  int b = blockIdx.x, t = threadIdx.x;
  float acc = 0.f, cn = 0.f;
  #pragma unroll
  for (int c = 0; c < 8; ++c){
    acc += partial[(size_t)(b*8 + c)*DD + t];
    cn  += cnt[b*8 + c];
  }
  float val = acc / cn;
  if (*flag) ((u16*)out)[b*DD + t] = f2bf(val);
  else       ((float*)out)[b*DD + t] = val;
}

// ---------------- host ----------------
extern "C" void kernel_launch(void* const* d_in, const int* in_sizes, int n_in,
                              void* d_out, int out_size, void* d_ws, size_t ws_size,
                              hipStream_t stream)
{
  (void)in_sizes; (void)n_in; (void)out_size; (void)ws_size;
  char* ws = (char*)d_ws;
  int*   flag   = (int*)(ws + OFF_FLAG);
  int*   starts = (int*)(ws + OFF_STARTS);
  float* BIN  = (float*)(ws + OFF_BIN);
  float* BQKV = (float*)(ws + OFF_BQKV);
  float* BO   = (float*)(ws + OFF_BO);
  float* B1   = (float*)(ws + OFF_B1);
  float* B2   = (float*)(ws + OFF_B2);
  float* LN1G = (float*)(ws + OFF_LN1G);
  float* LN1B = (float*)(ws + OFF_LN1B);
  float* LN2G = (float*)(ws + OFF_LN2G);
  float* LN2B = (float*)(ws + OFF_LN2B);
  u16* XB    = (u16*)(ws + OFF_XB);
  u16* WINB  = (u16*)(ws + OFF_WINB);
  u16* WQKVB = (u16*)(ws + OFF_WQKVB);
  u16* WOB   = (u16*)(ws + OFF_WOB);
  u16* W1B   = (u16*)(ws + OFF_W1B);
  u16* W2B   = (u16*)(ws + OFF_W2B);
  float* CUR = (float*)(ws + OFF_CUR);
  float* TMP = (float*)(ws + OFF_TMP);
  u16* CURB  = (u16*)(ws + OFF_CURB);
  u16* QKVB  = (u16*)(ws + OFF_QKVB);
  u16* ATTNOB= (u16*)(ws + OFF_ATTNOB);
  float* MASK= (float*)(ws + OFF_MASK);
  u16* VT    = (u16*)(ws + OFF_VT);
  float* RED = (float*)(ws + OFF_RED);
  float* CNT = (float*)(ws + OFF_CNT);

  detect_kernel<<<1, 256, 0, stream>>>((const unsigned*)d_in[0], flag);
  starts_kernel<<<1, 64, 0, stream>>>((const int*)d_in[1], starts);

  auto cb = [&](const void* s, u16* dp, int n){
    conv2bf16_kernel<<<(n + 1023)/1024, 256, 0, stream>>>(s, dp, n, flag);
  };
  auto cf = [&](const void* s, float* dp, int n){
    conv2f32_kernel<<<(n + 1023)/1024, 256, 0, stream>>>(s, dp, n, flag);
  };
  cb(d_in[0],  XB,    NTOT*INDIM);
  cb(d_in[2],  WINB,  DD*INDIM);
  cb(d_in[4],  WQKVB, LL*3*DD*DD);
  cb(d_in[6],  WOB,   LL*DD*DD);
  cb(d_in[8],  W1B,   LL*DFF*DD);
  cb(d_in[10], W2B,   LL*DD*DFF);
  cf(d_in[3],  BIN,   DD);
  cf(d_in[5],  BQKV,  LL*3*DD);
  cf(d_in[7],  BO,    LL*DD);
  cf(d_in[9],  B1,    LL*DFF);
  cf(d_in[11], B2,    LL*DD);
  cf(d_in[12], LN1G,  LL*DD);
  cf(d_in[13], LN1B,  LL*DD);
  cf(d_in[14], LN2G,  LL*DD);
  cf(d_in[15], LN2B,  LL*DD);

  gemm_bf16<<<dim3(NTOT/64, DD/64), 256, 0, stream>>>(
      XB, INDIM, WINB, INDIM, BIN, TMP, nullptr, DD, INDIM, 0);
  scatter_kernel<<<NTOT, 128, 0, stream>>>(TMP, (const int*)d_in[1], starts, CUR, CURB, MASK);

  for (int l = 0; l < LL; ++l){
    // QKV: 3 N-slices of 128
    wgemm_kernel<<<dim3(NTOT/64, 3), 256, 0, stream>>>(
        CURB, WQKVB + (size_t)l*3*DD*DD, BQKV + l*3*DD, 0,
        QKVB, 384, nullptr, nullptr, nullptr, nullptr);
    vtrans_kernel<<<dim3(NPER/64, HH, BB), 256, 0, stream>>>(QKVB, VT);
    fattn_kernel<<<dim3(NPER/64, HH, BB), 256, 0, stream>>>(QKVB, VT, ATTNOB);
    // Wo + residual + LN1
    wgemm_kernel<<<dim3(NTOT/64, 1), 256, 0, stream>>>(
        ATTNOB, WOB + (size_t)l*DD*DD, BO + l*DD, 1,
        nullptr, 0, CUR, CURB, LN1G + l*DD, LN1B + l*DD);
    // fused FFN + residual + LN2
    ffn_kernel<<<dim3(NTOT/64), 256, 0, stream>>>(
        CURB, W1B + (size_t)l*DFF*DD, W2B + (size_t)l*DD*DFF,
        B1 + l*DFF, B2 + l*DD, LN2G + l*DD, LN2B + l*DD, CUR, CURB);
  }

  reduce1_kernel<<<dim3(BB, 8), 128, 0, stream>>>(CUR, MASK, RED, CNT);
  reduce2_kernel<<<BB, 128, 0, stream>>>(RED, CNT, flag, d_out);
}

// Round 7
// 508.703 us; speedup vs baseline: 1.7402x; 1.2106x over previous
//
#include <hip/hip_runtime.h>
#include <hip/hip_bf16.h>
#include <stdint.h>

// ---------------- static problem sizes ----------------
#define BB    32
#define NPER  1024
#define NTOT  32768
#define DD    128
#define HH    4
#define HD    32
#define LL    3
#define DFF   2048
#define INDIM 64
#define QKSCALE 0.17677669529663687f

typedef unsigned short u16;
typedef short bf16x8 __attribute__((ext_vector_type(8)));   // 8 bf16 (4 VGPRs)
typedef float f32x4 __attribute__((ext_vector_type(4)));

// address-space casts for global_load_lds (direct global->LDS DMA)
#define AS_GLOBAL(p) ((const __attribute__((address_space(1))) void*)(p))
#define AS_LDS(p)    ((__attribute__((address_space(3))) void*)(p))

__device__ __forceinline__ float bf2f(u16 v){
  unsigned u = ((unsigned)v) << 16; float f; __builtin_memcpy(&f, &u, 4); return f;
}
__device__ __forceinline__ u16 f2bf(float f){
  unsigned u; __builtin_memcpy(&u, &f, 4);
  unsigned lsb = (u >> 16) & 1u;
  u += 0x7fffu + lsb;              // round-to-nearest-even
  return (u16)(u >> 16);
}

// ---------------- workspace layout (bytes) ----------------
constexpr size_t OFF_FLAG   = 0;
constexpr size_t OFF_STARTS = 256;
constexpr size_t OFF_BIN    = 1024;
constexpr size_t OFF_BQKV   = OFF_BIN   + 128*4;
constexpr size_t OFF_BO     = OFF_BQKV  + 1152*4;
constexpr size_t OFF_B1     = OFF_BO    + 384*4;
constexpr size_t OFF_B2     = OFF_B1    + 6144*4;
constexpr size_t OFF_LN1G   = OFF_B2    + 384*4;
constexpr size_t OFF_LN1B   = OFF_LN1G  + 384*4;
constexpr size_t OFF_LN2G   = OFF_LN1B  + 384*4;
constexpr size_t OFF_LN2B   = OFF_LN2G  + 384*4;
constexpr size_t OFF_XB     = 40960;
constexpr size_t OFF_WINB   = OFF_XB    + (size_t)2097152*2;
constexpr size_t OFF_WQKVB  = OFF_WINB  + (size_t)8192*2;
constexpr size_t OFF_WOB    = OFF_WQKVB + (size_t)147456*2;
constexpr size_t OFF_W1B    = OFF_WOB   + (size_t)49152*2;
constexpr size_t OFF_W2B    = OFF_W1B   + (size_t)786432*2;
constexpr size_t OFF_CUR    = OFF_W2B   + (size_t)786432*2;
constexpr size_t OFF_TMP    = OFF_CUR   + (size_t)4194304*4;
constexpr size_t OFF_CURB   = OFF_TMP   + (size_t)4194304*4;
constexpr size_t OFF_QKVB   = OFF_CURB  + (size_t)4194304*2;
constexpr size_t OFF_ATTNOB = OFF_QKVB  + (size_t)12582912*2;
constexpr size_t OFF_ACTB   = OFF_ATTNOB+ (size_t)4194304*2;     // (unused now)
constexpr size_t OFF_MASK   = OFF_ACTB  + (size_t)16777216*2;
constexpr size_t OFF_VT     = OFF_MASK  + (size_t)NTOT*4;
constexpr size_t OFF_RED    = OFF_VT    + (size_t)4096*1024*2;
constexpr size_t OFF_CNT    = OFF_RED   + (size_t)32*8*128*4;

// ---------------- dtype detection ----------------
__device__ __forceinline__ int plaus(unsigned bits){
  if ((bits << 1) == 0u) return 1;
  unsigned e = (bits >> 23) & 0xFFu;
  return (e >= 100u && e <= 140u) ? 1 : 0;
}
__global__ void detect_kernel(const unsigned* __restrict__ x, int* __restrict__ flag){
  __shared__ int red[256];
  int t = threadIdx.x, c = 0;
  for (int i = t; i < 2048; i += 256){
    unsigned w = x[i];
    c += (plaus(w << 16) & plaus(w & 0xFFFF0000u));
  }
  red[t] = c; __syncthreads();
  for (int s = 128; s > 0; s >>= 1){ if (t < s) red[t] += red[t+s]; __syncthreads(); }
  if (t == 0) *flag = (red[0] >= 1229) ? 1 : 0;
}

__global__ void starts_kernel(const int* __restrict__ batch, int* __restrict__ starts){
  int b = threadIdx.x;
  if (b < BB){
    int lo = 0, hi = NTOT;
    while (lo < hi){ int mid = (lo + hi) >> 1; if (batch[mid] < b) lo = mid + 1; else hi = mid; }
    starts[b] = lo;
  }
}

// ---------------- fused conversion of all 15 float tensors (1 launch) ----------------
struct ConvSeg { const void* src; void* dst; int n; int tobf; };
struct ConvArgs { ConvSeg s[15]; };

__global__ __launch_bounds__(256) void convall_kernel(ConvArgs a, const int* __restrict__ flag){
  const int isb = *flag;
  const int blk = blockIdx.x;
  int seg = -1, base = 0, lb = 0;
  #pragma unroll
  for (int i = 0; i < 15; ++i){
    int nb = (a.s[i].n + 1023) >> 10;
    if (seg < 0){
      if (blk < base + nb){ seg = i; lb = blk - base; }
      base += nb;
    }
  }
  const ConvSeg sg = a.s[seg];
  const int idx = lb*1024 + threadIdx.x*4;
  if (idx >= sg.n) return;
  if (sg.tobf){
    u16* dst = (u16*)sg.dst + idx;
    if (isb){
      *(uint2*)dst = *(const uint2*)((const u16*)sg.src + idx);
    } else {
      const float* s4 = (const float*)sg.src + idx;
      dst[0] = f2bf(s4[0]); dst[1] = f2bf(s4[1]);
      dst[2] = f2bf(s4[2]); dst[3] = f2bf(s4[3]);
    }
  } else {
    float* dst = (float*)sg.dst + idx;
    if (isb){
      const u16* s4 = (const u16*)sg.src + idx;
      dst[0] = bf2f(s4[0]); dst[1] = bf2f(s4[1]);
      dst[2] = bf2f(s4[2]); dst[3] = bf2f(s4[3]);
    } else {
      *(float4*)dst = *(const float4*)((const float*)sg.src + idx);
    }
  }
}

// ---------------- legacy small GEMM (input projection only) ----------------
__global__ __launch_bounds__(256) void gemm_bf16(
    const u16* __restrict__ A, int lda,
    const u16* __restrict__ W, int ldw,
    const float* __restrict__ bias,
    float* __restrict__ Cf, u16* __restrict__ Cb,
    int N, int K, int flags)
{
  __shared__ __align__(16) u16 At[64][32];
  __shared__ __align__(16) u16 Wt[64][32];
  const int t = threadIdx.x;
  const int m0 = blockIdx.x * 64, n0 = blockIdx.y * 64;
  const int wave = t >> 6, lane = t & 63;
  const int quad = lane >> 4, l16 = lane & 15;
  const int lr = t >> 2, lc = (t & 3) * 8;

  f32x4 acc[4];
  #pragma unroll
  for (int i = 0; i < 4; ++i){ acc[i][0]=0.f; acc[i][1]=0.f; acc[i][2]=0.f; acc[i][3]=0.f; }

  const u16* Arow = A + (size_t)(m0 + lr) * lda + lc;
  const u16* Wrow = W + (size_t)(n0 + lr) * ldw + lc;

  for (int k0 = 0; k0 < K; k0 += 32){
    uint4 av = *(const uint4*)(Arow + k0);
    uint4 wv = *(const uint4*)(Wrow + k0);
    __syncthreads();
    *(uint4*)&At[lr][lc] = av;
    *(uint4*)&Wt[lr][lc] = wv;
    __syncthreads();
    bf16x8 af = *(const bf16x8*)&At[wave*16 + l16][quad*8];
    #pragma unroll
    for (int nt = 0; nt < 4; ++nt){
      bf16x8 wf = *(const bf16x8*)&Wt[nt*16 + l16][quad*8];
      acc[nt] = __builtin_amdgcn_mfma_f32_16x16x32_bf16(af, wf, acc[nt], 0, 0, 0);
    }
  }
  const int row = m0 + wave*16 + quad*4;
  #pragma unroll
  for (int nt = 0; nt < 4; ++nt){
    const int col = n0 + nt*16 + l16;
    const float bv = bias ? bias[col] : 0.f;
    #pragma unroll
    for (int r = 0; r < 4; ++r){
      size_t idx = (size_t)(row + r) * N + col;
      float v = acc[nt][r] + bv;
      if (flags & 1) v = fmaxf(v, 0.f);
      if (Cf) Cf[idx] = v;
      if (Cb) Cb[idx] = f2bf(v);
    }
  }
}

// ---------------- scatter projected nodes into padded layout + mask ----------------
__global__ __launch_bounds__(128) void scatter_kernel(
    const float* __restrict__ hlin, const int* __restrict__ batch,
    const int* __restrict__ starts, float* __restrict__ cur,
    u16* __restrict__ curb, float* __restrict__ mask)
{
  int i = blockIdx.x, t = threadIdx.x;
  int g = batch[i];
  int p = i - starts[g];
  float v = hlin[(size_t)i*DD + t];
  float s = v;
  #pragma unroll
  for (int off = 32; off; off >>= 1) s += __shfl_xor(s, off);
  __shared__ float sh[2];
  if ((t & 63) == 0) sh[t >> 6] = s;
  __syncthreads();
  float rowsum = sh[0] + sh[1];
  if ((unsigned)p < (unsigned)NPER && (unsigned)g < (unsigned)BB){
    size_t j = (size_t)g*NPER + p;
    cur[j*DD + t]  = v;
    curb[j*DD + t] = f2bf(v);
    if (t == 0) mask[j] = (rowsum != 0.f) ? 1.f : 0.f;
  }
}

// ---------------- MFMA flash attention v2 ----------------
// Operand-swapped QK (A=K, B=Q): C[s][q] -> P written as packed b64; in-lane
// row-sum + 2 shfl. K/V staged by global_load_lds, double-buffered, chunk-major
// LDS layout (slot=c*64+r / cv*32+d) -> phase-conflict-free b128 frag reads.
__global__ __launch_bounds__(256) void fattn_kernel(
    const u16* __restrict__ qkvb,   // [NTOT][384]
    const u16* __restrict__ vt,     // [B*H*HD][NPER]
    u16* __restrict__ attnob)       // [NTOT][128]
{
  __shared__ __align__(16) u16 Klds[2][2048];      // [c(4)][r(64)][8]
  __shared__ __align__(16) u16 Vl[2][2048];        // [cv(8)][d(32)][8]
  __shared__ __align__(16) u16 Pl[4][16*72];       // per-wave P [q][s], pitch 72

  const int t = threadIdx.x;
  const int wave = t >> 6, lane = t & 63;
  const int quad = lane >> 4, l16 = lane & 15;
  const int q0 = blockIdx.x * 64;
  const int h = blockIdx.y, b = blockIdx.z;
  const size_t qkvbase = (size_t)b * NPER * 384;
  const u16* Kg = qkvb + qkvbase + 128 + h*HD;              // K rows, stride 384
  const u16* Vg = vt + (size_t)((b*HH + h)*HD) * NPER;      // V^T rows, stride 1024

  // Q B-frag, scaled: B[n=q=l16][k=quad*8+j]
  bf16x8 qf;
  {
    const u16* qp = qkvb + qkvbase + (size_t)(q0 + wave*16 + l16)*384 + h*HD + quad*8;
    uint4 qv = *(const uint4*)qp;
    u16 raw[8]; __builtin_memcpy(raw, &qv, 16);
    #pragma unroll
    for (int j = 0; j < 8; ++j) qf[j] = (short)f2bf(bf2f(raw[j]) * QKSCALE);
  }

  // DMA staging: wave w stages K chunk c=w (rows=lane) and V slots w*64+lane.
  const int vcv = wave*2 + (lane >> 5), vd = lane & 31;
  auto stage = [&](int buf, int kt){
    __builtin_amdgcn_global_load_lds(
        AS_GLOBAL(Kg + (size_t)(kt*64 + lane)*384 + wave*8),
        AS_LDS(&Klds[buf][wave*64*8]), 16, 0, 0);
    __builtin_amdgcn_global_load_lds(
        AS_GLOBAL(Vg + (size_t)vd*NPER + kt*64 + vcv*8),
        AS_LDS(&Vl[buf][wave*64*8]), 16, 0, 0);
  };

  float lsum = 0.f;                                // sum for q=l16 (replicated over quads)
  f32x4 o0 = {0.f,0.f,0.f,0.f}, o1 = {0.f,0.f,0.f,0.f};
  u16* Pw = &Pl[wave][0];

  stage(0, 0);
  asm volatile("s_waitcnt vmcnt(0)" ::: "memory");
  __syncthreads();

  for (int kt = 0; kt < 16; ++kt){
    const int buf = kt & 1;
    if (kt + 1 < 16) stage(buf ^ 1, kt + 1);       // DMA in flight across compute

    // S^T tile: sfr[nt] = K_tile x Q^T -> rows s=nt*16+quad*4+r, col q=l16
    f32x4 sfr[4];
    #pragma unroll
    for (int nt = 0; nt < 4; ++nt){
      bf16x8 kf = *(const bf16x8*)&Klds[buf][(quad*64 + nt*16 + l16)*8];
      f32x4 z = {0.f,0.f,0.f,0.f};
      sfr[nt] = __builtin_amdgcn_mfma_f32_16x16x32_bf16(kf, qf, z, 0, 0, 0);
    }

    // exp -> packed bf16 P[q][s] (b64 writes), in-lane partial sum
    float ps = 0.f;
    #pragma unroll
    for (int nt = 0; nt < 4; ++nt){
      float e0 = __expf(sfr[nt][0]), e1 = __expf(sfr[nt][1]);
      float e2 = __expf(sfr[nt][2]), e3 = __expf(sfr[nt][3]);
      ps += (e0 + e1) + (e2 + e3);
      uint2 w;
      w.x = (unsigned)f2bf(e0) | ((unsigned)f2bf(e1) << 16);
      w.y = (unsigned)f2bf(e2) | ((unsigned)f2bf(e3) << 16);
      *(uint2*)&Pw[l16*72 + nt*16 + quad*4] = w;
    }
    ps += __shfl_xor(ps, 16);
    ps += __shfl_xor(ps, 32);
    lsum += ps;
    asm volatile("s_waitcnt lgkmcnt(0)" ::: "memory");   // P write -> A-frag read

    // O += P V : A=P[q][s], B=V^T[d][s]
    #pragma unroll
    for (int kk = 0; kk < 2; ++kk){
      bf16x8 pf = *(const bf16x8*)&Pw[l16*72 + kk*32 + quad*8];
      bf16x8 v0 = *(const bf16x8*)&Vl[buf][((kk*4 + quad)*32 + l16)*8];
      bf16x8 v1 = *(const bf16x8*)&Vl[buf][((kk*4 + quad)*32 + 16 + l16)*8];
      o0 = __builtin_amdgcn_mfma_f32_16x16x32_bf16(pf, v0, o0, 0, 0, 0);
      o1 = __builtin_amdgcn_mfma_f32_16x16x32_bf16(pf, v1, o1, 0, 0, 0);
    }

    if (kt + 1 < 16){
      asm volatile("s_waitcnt vmcnt(0)" ::: "memory");   // own DMAs for kt+1 done
      __syncthreads();                                   // all waves' buf reads done
    }
  }

  // epilogue: O rows q=quad*4+r, col d=l16; lsum lives at lane l16=q
  #pragma unroll
  for (int r = 0; r < 4; ++r){
    float inv = 1.f / __shfl(lsum, quad*4 + r);
    int row = q0 + wave*16 + quad*4 + r;
    size_t base = (size_t)(b*NPER + row)*DD + h*HD;
    attnob[base + l16]      = f2bf(o0[r] * inv);
    attnob[base + 16 + l16] = f2bf(o1[r] * inv);
  }
}

// ---------------- LN epilogue (wave owns 16 rows): out = LN(resid + O + bias) ----------------
__device__ __forceinline__ void epilogue_ln64(
    const f32x4 O[8], int m0, int wave, int quad, int l16,
    const float* __restrict__ bias, const float* __restrict__ g,
    const float* __restrict__ beta, float* __restrict__ cur,
    u16* __restrict__ curb)
{
  #pragma unroll
  for (int rr = 0; rr < 4; ++rr){
    int row = m0 + wave*16 + quad*4 + rr;
    float vs[8], sum = 0.f;
    #pragma unroll
    for (int nt = 0; nt < 8; ++nt){
      int col = nt*16 + l16;
      float v = O[nt][rr] + bias[col] + cur[(size_t)row*DD + col];
      vs[nt] = v; sum += v;
    }
    sum += __shfl_xor(sum, 1); sum += __shfl_xor(sum, 2);
    sum += __shfl_xor(sum, 4); sum += __shfl_xor(sum, 8);
    float mean = sum * (1.f/DD);
    float sq = 0.f;
    #pragma unroll
    for (int nt = 0; nt < 8; ++nt){ float d = vs[nt] - mean; sq += d*d; }
    sq += __shfl_xor(sq, 1); sq += __shfl_xor(sq, 2);
    sq += __shfl_xor(sq, 4); sq += __shfl_xor(sq, 8);
    float rs = rsqrtf(sq * (1.f/DD) + 1e-5f);
    #pragma unroll
    for (int nt = 0; nt < 8; ++nt){
      int col = nt*16 + l16;
      float o = (vs[nt] - mean)*rs*g[col] + beta[col];
      cur[(size_t)row*DD + col]  = o;
      curb[(size_t)row*DD + col] = f2bf(o);
    }
  }
}

// ---------------- 64-row-block GEMM, W (128x128 slice) in LDS, A-frags in regs ----------------
// mode 0: outb write (QKV); nb==2 (V slice) writes transposed VT instead.
// mode 1: LN epilogue (Wo + LN1)
__global__ __launch_bounds__(256) void wgemm_kernel(
    const u16* __restrict__ A,        // [M][128] bf16
    const u16* __restrict__ Wbase,    // [gridDim.y*128][128] bf16
    const float* __restrict__ biasb,  // [gridDim.y*128]
    int mode,
    u16* __restrict__ outb, int opitch,
    u16* __restrict__ vtout,
    float* __restrict__ cur, u16* __restrict__ curb,
    const float* __restrict__ g, const float* __restrict__ beta)
{
  __shared__ __align__(16) u16 Wl[16384];          // 128x128, XOR-swizzled chunks
  const int t = threadIdx.x, wave = t >> 6, lane = t & 63;
  const int quad = lane >> 4, l16 = lane & 15;
  const int m0 = blockIdx.x * 64, nb = blockIdx.y;
  const u16* Wsl = Wbase + (size_t)nb * 16384;
  const float* bias = biasb + nb * 128;

  #pragma unroll
  for (int j = 0; j < 8; ++j){
    int s = t + 256*j;
    int r = s >> 4, cx = (s & 15) ^ (r & 15);
    *(uint4*)&Wl[s*8] = *(const uint4*)(Wsl + (size_t)r*128 + cx*8);
  }
  bf16x8 af[4];
  #pragma unroll
  for (int kk = 0; kk < 4; ++kk)
    af[kk] = *(const bf16x8*)(A + (size_t)(m0 + wave*16 + l16)*128 + kk*32 + quad*8);
  __syncthreads();

  f32x4 O[8];
  #pragma unroll
  for (int nt = 0; nt < 8; ++nt){ O[nt][0]=0.f; O[nt][1]=0.f; O[nt][2]=0.f; O[nt][3]=0.f; }

  #pragma unroll
  for (int nt = 0; nt < 8; ++nt){
    int row = nt*16 + l16;
    bf16x8 wf[4];
    #pragma unroll
    for (int kk = 0; kk < 4; ++kk)
      wf[kk] = *(const bf16x8*)&Wl[(row*16 + ((kk*4 + quad) ^ l16))*8];
    #pragma unroll
    for (int kk = 0; kk < 4; ++kk)
      O[nt] = __builtin_amdgcn_mfma_f32_16x16x32_bf16(af[kk], wf[kk], O[nt], 0, 0, 0);
  }

  if (mode == 0){
    if (nb == 2 && vtout){
      // V slice: write directly transposed into VT (replaces vtrans kernel)
      int rowb = m0 + wave*16 + quad*4;
      int bg = rowb >> 10, s = rowb & 1023;        // all 4 rr in same graph
      #pragma unroll
      for (int nt = 0; nt < 8; ++nt){
        int col = nt*16 + l16;
        int hh = col >> 5, d = col & 31;
        float v0 = O[nt][0] + bias[col], v1 = O[nt][1] + bias[col];
        float v2 = O[nt][2] + bias[col], v3 = O[nt][3] + bias[col];
        uint2 w;
        w.x = (unsigned)f2bf(v0) | ((unsigned)f2bf(v1) << 16);
        w.y = (unsigned)f2bf(v2) | ((unsigned)f2bf(v3) << 16);
        *(uint2*)(vtout + (size_t)((bg*HH + hh)*HD + d)*NPER + s) = w;
      }
    } else {
      #pragma unroll
      for (int rr = 0; rr < 4; ++rr){
        int row = m0 + wave*16 + quad*4 + rr;
        #pragma unroll
        for (int nt = 0; nt < 8; ++nt){
          int col = nt*16 + l16;
          outb[(size_t)row*opitch + nb*128 + col] = f2bf(O[nt][rr] + bias[col]);
        }
      }
    }
  } else {
    epilogue_ln64(O, m0, wave, quad, l16, bias, g, beta, cur, curb);
  }
}

// ---------------- fused FFN, 64-row blocks, double-buffered W LDS via global_load_lds ----------------
__global__ __launch_bounds__(256, 2) void ffn_kernel(
    const u16* __restrict__ Ag,       // CURB [M][128]
    const u16* __restrict__ W1g,      // [2048][128]
    const u16* __restrict__ W2g,      // [128][2048]
    const float* __restrict__ b1,
    const float* __restrict__ b2,
    const float* __restrict__ g, const float* __restrict__ beta,
    float* __restrict__ cur, u16* __restrict__ curb)
{
  __shared__ __align__(16) u16 W1l[2][8192];       // 64x128 chunk, swizzled, x2 buf
  __shared__ __align__(16) u16 W2l[2][8192];       // 128x64 chunk, swizzled, x2 buf
  __shared__ __align__(16) u16 Pl[4][16*72];       // per-wave act, pitch 72

  const int t = threadIdx.x, wave = t >> 6, lane = t & 63;
  const int quad = lane >> 4, l16 = lane & 15;
  const int m0 = blockIdx.x * 64;
  u16* Pw = &Pl[wave][0];

  auto stage = [&](int buf, int dffc){
    #pragma unroll
    for (int i = 0; i < 4; ++i){
      const int s0 = wave*256 + i*64;
      const int s  = s0 + lane;
      { int r = s >> 4, cx = (s & 15) ^ (r & 15);
        __builtin_amdgcn_global_load_lds(
            AS_GLOBAL(W1g + (size_t)(dffc + r)*128 + cx*8),
            AS_LDS(&W1l[buf][s0*8]), 16, 0, 0); }
      { int r = s >> 3, cx = (s & 7) ^ (r & 7);
        __builtin_amdgcn_global_load_lds(
            AS_GLOBAL(W2g + (size_t)r*DFF + dffc + cx*8),
            AS_LDS(&W2l[buf][s0*8]), 16, 0, 0); }
    }
  };

  bf16x8 af[4];
  #pragma unroll
  for (int kk = 0; kk < 4; ++kk)
    af[kk] = *(const bf16x8*)(Ag + (size_t)(m0 + wave*16 + l16)*128 + kk*32 + quad*8);

  f32x4 O[8];
  #pragma unroll
  for (int nt = 0; nt < 8; ++nt){ O[nt][0]=0.f; O[nt][1]=0.f; O[nt][2]=0.f; O[nt][3]=0.f; }

  stage(0, 0);
  asm volatile("s_waitcnt vmcnt(0)" ::: "memory");
  __syncthreads();

  for (int c = 0; c < 32; ++c){
    const int buf = c & 1;
    if (c + 1 < 32) stage(buf ^ 1, (c + 1)*64);

    #pragma unroll
    for (int nt = 0; nt < 4; ++nt){
      int row = nt*16 + l16;
      bf16x8 wf[4];
      #pragma unroll
      for (int kk = 0; kk < 4; ++kk)
        wf[kk] = *(const bf16x8*)&W1l[buf][(row*16 + ((kk*4 + quad) ^ l16))*8];
      float b1v = b1[c*64 + row];
      f32x4 s = {0.f,0.f,0.f,0.f};
      #pragma unroll
      for (int kk = 0; kk < 4; ++kk)
        s = __builtin_amdgcn_mfma_f32_16x16x32_bf16(af[kk], wf[kk], s, 0, 0, 0);
      #pragma unroll
      for (int rr = 0; rr < 4; ++rr)
        Pw[(quad*4 + rr)*72 + nt*16 + l16] = f2bf(fmaxf(s[rr] + b1v, 0.f));
    }
    asm volatile("s_waitcnt lgkmcnt(0)" ::: "memory");

    bf16x8 pf[2];
    #pragma unroll
    for (int kk = 0; kk < 2; ++kk)
      pf[kk] = *(const bf16x8*)&Pw[l16*72 + kk*32 + quad*8];
    #pragma unroll
    for (int nt = 0; nt < 8; ++nt){
      int row = nt*16 + l16;
      bf16x8 wf[2];
      #pragma unroll
      for (int kk = 0; kk < 2; ++kk)
        wf[kk] = *(const bf16x8*)&W2l[buf][(row*8 + ((kk*4 + quad) ^ (l16 & 7)))*8];
      #pragma unroll
      for (int kk = 0; kk < 2; ++kk)
        O[nt] = __builtin_amdgcn_mfma_f32_16x16x32_bf16(pf[kk], wf[kk], O[nt], 0, 0, 0);
    }

    if (c + 1 < 32){
      asm volatile("s_waitcnt vmcnt(0)" ::: "memory");
      __syncthreads();
    }
  }

  epilogue_ln64(O, m0, wave, quad, l16, b2, g, beta, cur, curb);
}

// ---------------- final masked mean, two-stage ----------------
__global__ __launch_bounds__(128) void reduce1_kernel(
    const float* __restrict__ cur, const float* __restrict__ mask,
    float* __restrict__ partial, float* __restrict__ cnt)
{
  int b = blockIdx.x, c = blockIdx.y, t = threadIdx.x;
  float acc = 0.f, cn = 0.f;
  for (int s = c*128; s < c*128 + 128; ++s){
    float mk = mask[b*NPER + s];
    acc += cur[(size_t)(b*NPER + s)*DD + t] * mk;
    cn += mk;
  }
  partial[(size_t)(b*8 + c)*DD + t] = acc;
  if (t == 0) cnt[b*8 + c] = cn;
}
__global__ __launch_bounds__(128) void reduce2_kernel(
    const float* __restrict__ partial, const float* __restrict__ cnt,
    const int* __restrict__ flag, void* __restrict__ out)
{
  int b = blockIdx.x, t = threadIdx.x;
  float acc = 0.f, cn = 0.f;
  #pragma unroll
  for (int c = 0; c < 8; ++c){
    acc += partial[(size_t)(b*8 + c)*DD + t];
    cn  += cnt[b*8 + c];
  }
  float val = acc / cn;
  if (*flag) ((u16*)out)[b*DD + t] = f2bf(val);
  else       ((float*)out)[b*DD + t] = val;
}

// ---------------- host ----------------
extern "C" void kernel_launch(void* const* d_in, const int* in_sizes, int n_in,
                              void* d_out, int out_size, void* d_ws, size_t ws_size,
                              hipStream_t stream)
{
  (void)in_sizes; (void)n_in; (void)out_size; (void)ws_size;
  char* ws = (char*)d_ws;
  int*   flag   = (int*)(ws + OFF_FLAG);
  int*   starts = (int*)(ws + OFF_STARTS);
  float* BIN  = (float*)(ws + OFF_BIN);
  float* BQKV = (float*)(ws + OFF_BQKV);
  float* BO   = (float*)(ws + OFF_BO);
  float* B1   = (float*)(ws + OFF_B1);
  float* B2   = (float*)(ws + OFF_B2);
  float* LN1G = (float*)(ws + OFF_LN1G);
  float* LN1B = (float*)(ws + OFF_LN1B);
  float* LN2G = (float*)(ws + OFF_LN2G);
  float* LN2B = (float*)(ws + OFF_LN2B);
  u16* XB    = (u16*)(ws + OFF_XB);
  u16* WINB  = (u16*)(ws + OFF_WINB);
  u16* WQKVB = (u16*)(ws + OFF_WQKVB);
  u16* WOB   = (u16*)(ws + OFF_WOB);
  u16* W1B   = (u16*)(ws + OFF_W1B);
  u16* W2B   = (u16*)(ws + OFF_W2B);
  float* CUR = (float*)(ws + OFF_CUR);
  float* TMP = (float*)(ws + OFF_TMP);
  u16* CURB  = (u16*)(ws + OFF_CURB);
  u16* QKVB  = (u16*)(ws + OFF_QKVB);
  u16* ATTNOB= (u16*)(ws + OFF_ATTNOB);
  float* MASK= (float*)(ws + OFF_MASK);
  u16* VT    = (u16*)(ws + OFF_VT);
  float* RED = (float*)(ws + OFF_RED);
  float* CNT = (float*)(ws + OFF_CNT);

  detect_kernel<<<1, 256, 0, stream>>>((const unsigned*)d_in[0], flag);
  starts_kernel<<<1, 64, 0, stream>>>((const int*)d_in[1], starts);

  // one fused conversion launch for all 15 tensors
  ConvArgs ca;
  ca.s[0]  = { d_in[0],  XB,    NTOT*INDIM, 1 };
  ca.s[1]  = { d_in[2],  WINB,  DD*INDIM,   1 };
  ca.s[2]  = { d_in[4],  WQKVB, LL*3*DD*DD, 1 };
  ca.s[3]  = { d_in[6],  WOB,   LL*DD*DD,   1 };
  ca.s[4]  = { d_in[8],  W1B,   LL*DFF*DD,  1 };
  ca.s[5]  = { d_in[10], W2B,   LL*DD*DFF,  1 };
  ca.s[6]  = { d_in[3],  BIN,   DD,         0 };
  ca.s[7]  = { d_in[5],  BQKV,  LL*3*DD,    0 };
  ca.s[8]  = { d_in[7],  BO,    LL*DD,      0 };
  ca.s[9]  = { d_in[9],  B1,    LL*DFF,     0 };
  ca.s[10] = { d_in[11], B2,    LL*DD,      0 };
  ca.s[11] = { d_in[12], LN1G,  LL*DD,      0 };
  ca.s[12] = { d_in[13], LN1B,  LL*DD,      0 };
  ca.s[13] = { d_in[14], LN2G,  LL*DD,      0 };
  ca.s[14] = { d_in[15], LN2B,  LL*DD,      0 };
  int nblk = 0;
  for (int i = 0; i < 15; ++i) nblk += (ca.s[i].n + 1023) >> 10;
  convall_kernel<<<nblk, 256, 0, stream>>>(ca, flag);

  gemm_bf16<<<dim3(NTOT/64, DD/64), 256, 0, stream>>>(
      XB, INDIM, WINB, INDIM, BIN, TMP, nullptr, DD, INDIM, 0);
  scatter_kernel<<<NTOT, 128, 0, stream>>>(TMP, (const int*)d_in[1], starts, CUR, CURB, MASK);

  for (int l = 0; l < LL; ++l){
    // QKV: 3 N-slices of 128; V slice (nb=2) streams straight into VT (transposed)
    wgemm_kernel<<<dim3(NTOT/64, 3), 256, 0, stream>>>(
        CURB, WQKVB + (size_t)l*3*DD*DD, BQKV + l*3*DD, 0,
        QKVB, 384, VT, nullptr, nullptr, nullptr, nullptr);
    fattn_kernel<<<dim3(NPER/64, HH, BB), 256, 0, stream>>>(QKVB, VT, ATTNOB);
    // Wo + residual + LN1
    wgemm_kernel<<<dim3(NTOT/64, 1), 256, 0, stream>>>(
        ATTNOB, WOB + (size_t)l*DD*DD, BO + l*DD, 1,
        nullptr, 0, nullptr, CUR, CURB, LN1G + l*DD, LN1B + l*DD);
    // fused FFN + residual + LN2
    ffn_kernel<<<dim3(NTOT/64), 256, 0, stream>>>(
        CURB, W1B + (size_t)l*DFF*DD, W2B + (size_t)l*DD*DFF,
        B1 + l*DFF, B2 + l*DD, LN2G + l*DD, LN2B + l*DD, CUR, CURB);
  }

  reduce1_kernel<<<dim3(BB, 8), 128, 0, stream>>>(CUR, MASK, RED, CNT);
  reduce2_kernel<<<BB, 128, 0, stream>>>(RED, CNT, flag, d_out);
}